// Round 5
// baseline (118.263 us; speedup 1.0000x reference)
//
#include <hip/hip_runtime.h>
#include <math.h>

// Problem constants: B=8, N=4096, C=768, H=W=64, GROUPS=4.
#define BB 8
#define CC 768
#define HH 64
#define WW 64
#define NN 4096
#define GG 4
#define NCHUNK 6
#define CHUNK 128   /* channels per A1 block */

typedef __attribute__((ext_vector_type(8))) short short8;
typedef __attribute__((ext_vector_type(4))) float f32x4;

__device__ __forceinline__ unsigned short f2bf(float f) {   // RNE float->bf16
    union { float f; unsigned u; } v; v.f = f;
    unsigned r = v.u + 0x7FFFu + ((v.u >> 16) & 1u);
    return (unsigned short)(r >> 16);
}

// tanh-form GELU approx: v * sigmoid(1.5957691*v*(1+0.044715*v^2)).
// |err| <= ~3e-4 abs — far below the bf16 staging quantization already in use.
__device__ __forceinline__ float gelu_fast(float v) {
    const float z = 1.5957691216f * v * fmaf(0.044715f, v * v, 1.0f);
    return __fdividef(v, 1.0f + __expf(-z));
}

// ---------------------------------------------------------------------------
// A1: block = (b, h, chunk of 128 ch), 128 threads (2 waves).
// Phase 1 (per 32-col half): sliding 3x3 depthwise conv (batch-8 register
// prefetch), fast GELU; stage gelu AND center-x as bf16 in LDS.
// Phase 2 (MFMA): D[pos][n] = [gelu|xc](pos,256k) x blockdiag(off_w, wt_w):
// 8 x mfma_f32_16x16x32_bf16 per wave per half.
// Cols n<8 = off partials, n>=8 = wt partials -> offpart[chunk*16+n][gpos].
// ---------------------------------------------------------------------------
__global__ __launch_bounds__(128, 4) void dq_conv_mfma(
    const float* __restrict__ x,      // (B, N, C)
    const float* __restrict__ dw_w,   // (C, 9)
    const float* __restrict__ dw_b,   // (C,)
    const float* __restrict__ off_w,  // (8, C)
    const float* __restrict__ wt_w,   // (8, C)
    float* __restrict__ offpart)      // (NCHUNK, 16, B*N)
{
    __shared__ unsigned short gl[32][136];   // gelu, bf16, half-row
    __shared__ unsigned short xh[32][136];   // center x, bf16, half-row
    const int t = threadIdx.x;
    const int lane = t & 63, wv = t >> 6;
    int bid = blockIdx.x;
    const int chunk = bid % NCHUNK; bid /= NCHUNK;
    const int h = bid % HH;
    const int b = bid / HH;
    const int c = chunk * CHUNK + t;

    // ---- B fragments: blockdiag [off_w ; wt_w], built once, kept in regs ----
    const int n = lane & 15, kg = lane >> 4;
    short8 bfrag[8];
#pragma unroll
    for (int kt = 0; kt < 8; ++kt) {
        const bool isOff = (kt < 4);
        const bool valid = isOff ? (n < 8) : (n >= 8);
        const int krow = isOff ? kt : kt - 4;
        const float* wp = isOff ? (off_w + (n < 8 ? n : 0) * CC)
                                : (wt_w + (n >= 8 ? n - 8 : 0) * CC);
        const float* src = wp + chunk * CHUNK + krow * 32 + kg * 8;
        short8 bf;
#pragma unroll
        for (int j = 0; j < 8; ++j) {
            const float v = valid ? src[j] : 0.f;
            bf[j] = (short)f2bf(v);
        }
        bfrag[kt] = bf;
    }

    float w9[9];
#pragma unroll
    for (int j = 0; j < 9; ++j) w9[j] = dw_w[c * 9 + j];
    const float bias = dw_b[c];

    const float* rowc = x + (size_t)(b * NN + h * WW) * CC + c;
    const bool hm = (h > 0), hp = (h < HH - 1);
    const int RS = WW * CC;

    float cur0[8], cur1[8], cur2[8], nxt0[8], nxt1[8], nxt2[8];
    float pl0 = 0.f, pl1 = 0.f, pl2 = 0.f;

#pragma unroll
    for (int j = 0; j < 8; ++j) {
        const float* p = rowc + (size_t)j * CC;
        cur1[j] = p[0];
        cur0[j] = hm ? p[-RS] : 0.f;
        cur2[j] = hp ? p[RS] : 0.f;
    }

    for (int wb = 0; wb < 8; ++wb) {
        if (wb < 7) {
#pragma unroll
            for (int j = 0; j < 8; ++j) {
                const float* p = rowc + (size_t)(wb * 8 + 8 + j) * CC;
                nxt1[j] = p[0];
                nxt0[j] = hm ? p[-RS] : 0.f;
                nxt2[j] = hp ? p[RS] : 0.f;
            }
        } else {
#pragma unroll
            for (int j = 0; j < 8; ++j) { nxt0[j] = 0.f; nxt1[j] = 0.f; nxt2[j] = 0.f; }
        }
#pragma unroll
        for (int j = 0; j < 8; ++j) {
            const float l0 = j ? cur0[j - 1] : pl0;
            const float l1 = j ? cur1[j - 1] : pl1;
            const float l2 = j ? cur2[j - 1] : pl2;
            const float r0 = (j == 7) ? nxt0[0] : cur0[j + 1];
            const float r1 = (j == 7) ? nxt1[0] : cur1[j + 1];
            const float r2 = (j == 7) ? nxt2[0] : cur2[j + 1];
            float conv = l0 * w9[0] + cur0[j] * w9[1] + r0 * w9[2]
                       + l1 * w9[3] + cur1[j] * w9[4] + r1 * w9[5]
                       + l2 * w9[6] + cur2[j] * w9[7] + r2 * w9[8];
            const int wl = (wb & 3) * 8 + j;     // row within half
            gl[wl][t] = f2bf(gelu_fast(conv + bias));
            xh[wl][t] = f2bf(cur1[j]);
        }
        pl0 = cur0[7]; pl1 = cur1[7]; pl2 = cur2[7];
#pragma unroll
        for (int j = 0; j < 8; ++j) { cur0[j] = nxt0[j]; cur1[j] = nxt1[j]; cur2[j] = nxt2[j]; }

        if (wb == 3 || wb == 7) {
            const int half = wb >> 2;
            __syncthreads();
            // ---- MFMA: wave wv covers positions wv*16..wv*16+15 of this half
            f32x4 acc = {0.f, 0.f, 0.f, 0.f};
            const int arow = wv * 16 + n;
#pragma unroll
            for (int kt = 0; kt < 4; ++kt) {
                const short8 a = *(const short8*)&gl[arow][kt * 32 + kg * 8];
                acc = __builtin_amdgcn_mfma_f32_16x16x32_bf16(a, bfrag[kt], acc, 0, 0, 0);
            }
#pragma unroll
            for (int kt = 0; kt < 4; ++kt) {
                const short8 a = *(const short8*)&xh[arow][kt * 32 + kg * 8];
                acc = __builtin_amdgcn_mfma_f32_16x16x32_bf16(a, bfrag[4 + kt], acc, 0, 0, 0);
            }
            // D: col = n = lane&15, rows kg*4..kg*4+3 (contiguous positions)
            const int posl = half * 32 + wv * 16 + kg * 4;
            const size_t gpos = (size_t)(b * NN + h * WW) + posl;
            float4 st; st.x = acc[0]; st.y = acc[1]; st.z = acc[2]; st.w = acc[3];
            *(float4*)&offpart[((size_t)(chunk * 16 + n)) * (BB * NN) + gpos] = st;
            if (wb == 3) __syncthreads();
        }
    }
}

// ---------------------------------------------------------------------------
// B (fused): per-position combine (96 partials -> 8 coords, in-block) +
// bilinear border sampling. 192 threads, 4 channels/thread, float4 I/O.
// ---------------------------------------------------------------------------
__global__ __launch_bounds__(192) void dq_sample_fused(
    const float* __restrict__ x,        // (B, N, C)
    const float* __restrict__ offpart,  // (NCHUNK, 16, B*N)
    const float* __restrict__ off_b,
    const float* __restrict__ wt_b,
    float* __restrict__ out)            // (B, N, C)
{
    __shared__ float part[96];
    __shared__ float ixy[8];            // ix[4], iy[4]
    const int t = threadIdx.x;
    const int p = blockIdx.x;           // over B*N
    const int b = p >> 12;
    const int hw = p & 4095;
    const int h = hw >> 6, w = hw & 63;

    if (t < 96) part[t] = offpart[(size_t)t * (BB * NN) + p];
    __syncthreads();
    if (t < 8) {
        float so = 0.f, sw = 0.f;
#pragma unroll
        for (int ch = 0; ch < NCHUNK; ++ch) {
            so += part[ch * 16 + t];
            sw += part[ch * 16 + 8 + t];
        }
        const float sig = 1.f / (1.f + __expf(-(sw + wt_b[t])));
        const float val = (so + off_b[t]) * sig;
        if (t < 4) {
            const float shx = (t == 2) ? -1.f : ((t == 3) ? 1.f : 0.f);
            ixy[t] = fminf(fmaxf((float)w + val + shx, 0.f), (float)(WW - 1));
        } else {
            const int g = t - 4;
            const float shy = (g == 0) ? -1.f : ((g == 1) ? 1.f : 0.f);
            ixy[4 + g] = fminf(fmaxf((float)h + val + shy, 0.f), (float)(HH - 1));
        }
    }
    __syncthreads();

    const int g = t / 48;               // 48 threads x 4ch = 192 ch per group
    const float ix = ixy[g], iy = ixy[4 + g];
    const float x0f = floorf(ix), y0f = floorf(iy);
    const float wx = ix - x0f, wy = iy - y0f;
    const int x0 = (int)x0f, y0 = (int)y0f;
    const int x1 = min(x0 + 1, WW - 1), y1 = min(y0 + 1, HH - 1);
    const int c4 = t * 4;
    const float* xb = x + (size_t)b * NN * CC;
    const float4 v00 = *(const float4*)(xb + (size_t)(y0 * WW + x0) * CC + c4);
    const float4 v01 = *(const float4*)(xb + (size_t)(y0 * WW + x1) * CC + c4);
    const float4 v10 = *(const float4*)(xb + (size_t)(y1 * WW + x0) * CC + c4);
    const float4 v11 = *(const float4*)(xb + (size_t)(y1 * WW + x1) * CC + c4);
    const float w00 = (1.f - wx) * (1.f - wy), w01 = wx * (1.f - wy);
    const float w10 = (1.f - wx) * wy,         w11 = wx * wy;
    float4 r;
    r.x = v00.x * w00 + v01.x * w01 + v10.x * w10 + v11.x * w11;
    r.y = v00.y * w00 + v01.y * w01 + v10.y * w10 + v11.y * w11;
    r.z = v00.z * w00 + v01.z * w01 + v10.z * w10 + v11.z * w11;
    r.w = v00.w * w00 + v01.w * w01 + v10.w * w10 + v11.w * w11;
    *(float4*)(out + (size_t)p * CC + c4) = r;
}

// ---------------------------------------------------------------------------
// Fallback (small ws): round-1 fused offsets kernel + ixiy-based sampler.
// ---------------------------------------------------------------------------
__global__ __launch_bounds__(256) void dqshift_offsets_kernel(
    const float* __restrict__ x, const float* __restrict__ dw_w,
    const float* __restrict__ dw_b, const float* __restrict__ off_w,
    const float* __restrict__ off_b, const float* __restrict__ wt_w,
    const float* __restrict__ wt_b, float* __restrict__ ixiy)
{
    const int wave = threadIdx.x >> 6;
    const int lane = threadIdx.x & 63;
    const int p = blockIdx.x * 4 + wave;
    const int b = p >> 12;
    const int hw = p & 4095;
    const int h = hw >> 6;
    const int w = hw & 63;
    const float* xb = x + (size_t)b * NN * CC;
    float accO[8], accW[8];
#pragma unroll
    for (int o = 0; o < 8; ++o) { accO[o] = 0.f; accW[o] = 0.f; }
    for (int k = 0; k < CC / 64; ++k) {
        const int c = lane + (k << 6);
        float conv = 0.f, xc = 0.f;
#pragma unroll
        for (int dy = -1; dy <= 1; ++dy) {
            const int hh = h + dy;
            const bool vy = (hh >= 0) && (hh < HH);
#pragma unroll
            for (int dx = -1; dx <= 1; ++dx) {
                const int ww = w + dx;
                const bool vv = vy && (ww >= 0) && (ww < WW);
                const float tt = vv ? xb[(size_t)(hh * WW + ww) * CC + c] : 0.f;
                if (dy == 0 && dx == 0) xc = tt;
                conv = fmaf(tt, dw_w[c * 9 + (dy + 1) * 3 + (dx + 1)], conv);
            }
        }
        const float gv = conv + dw_b[c];
        const float gle = 0.5f * gv * (1.0f + erff(gv * 0.70710678118654752f));
#pragma unroll
        for (int o = 0; o < 8; ++o) {
            accO[o] = fmaf(gle, off_w[o * CC + c], accO[o]);
            accW[o] = fmaf(xc, wt_w[o * CC + c], accW[o]);
        }
    }
#pragma unroll
    for (int o = 0; o < 8; ++o) {
#pragma unroll
        for (int s = 32; s > 0; s >>= 1) {
            accO[o] += __shfl_xor(accO[o], s, 64);
            accW[o] += __shfl_xor(accW[o], s, 64);
        }
    }
    if (lane == 0) {
        const float shx[4] = {0.f, 0.f, -1.f, 1.f};
        const float shy[4] = {-1.f, 1.f, 0.f, 0.f};
#pragma unroll
        for (int g = 0; g < 4; ++g) {
            const float sx = 1.f / (1.f + expf(-(accW[g] + wt_b[g])));
            const float sy = 1.f / (1.f + expf(-(accW[4 + g] + wt_b[4 + g])));
            const float ox = (accO[g] + off_b[g]) * sx + shx[g];
            const float oy = (accO[4 + g] + off_b[4 + g]) * sy + shy[g];
            const float ix = fminf(fmaxf((float)w + ox, 0.f), (float)(WW - 1));
            const float iy = fminf(fmaxf((float)h + oy, 0.f), (float)(HH - 1));
            const int idx = (b * GG + g) * NN + hw;
            ixiy[idx] = ix;
            ixiy[BB * GG * NN + idx] = iy;
        }
    }
}

__global__ __launch_bounds__(256) void dqshift_sample_kernel(
    const float* __restrict__ x,
    const float* __restrict__ ixiy,
    float* __restrict__ out)
{
    const int p = blockIdx.x;
    const int b = p >> 12;
    const int hw = p & 4095;
    const float* xb = x + (size_t)b * NN * CC;
    float* ob = out + (size_t)p * CC;

#pragma unroll
    for (int k = 0; k < 3; ++k) {
        const int c = threadIdx.x + (k << 8);
        const int g = c / (CC / GG);
        const int idx = (b * GG + g) * NN + hw;
        const float ix = ixiy[idx];
        const float iy = ixiy[BB * GG * NN + idx];
        const float x0f = floorf(ix);
        const float y0f = floorf(iy);
        const float wx = ix - x0f;
        const float wy = iy - y0f;
        const int x0 = (int)x0f;
        const int y0 = (int)y0f;
        const int x1 = min(x0 + 1, WW - 1);
        const int y1 = min(y0 + 1, HH - 1);
        const float* r0 = xb + (size_t)(y0 * WW) * CC + c;
        const float* r1 = xb + (size_t)(y1 * WW) * CC + c;
        const float v00 = r0[(size_t)x0 * CC];
        const float v01 = r0[(size_t)x1 * CC];
        const float v10 = r1[(size_t)x0 * CC];
        const float v11 = r1[(size_t)x1 * CC];
        ob[c] = v00 * (1.f - wx) * (1.f - wy) + v01 * wx * (1.f - wy)
              + v10 * (1.f - wx) * wy + v11 * wx * wy;
    }
}

extern "C" void kernel_launch(void* const* d_in, const int* in_sizes, int n_in,
                              void* d_out, int out_size, void* d_ws, size_t ws_size,
                              hipStream_t stream) {
    const float* x     = (const float*)d_in[0];
    const float* dw_w  = (const float*)d_in[1];
    const float* dw_b  = (const float*)d_in[2];
    const float* off_w = (const float*)d_in[3];
    const float* off_b = (const float*)d_in[4];
    const float* wt_w  = (const float*)d_in[5];
    const float* wt_b  = (const float*)d_in[6];

    float* ixiy = (float*)d_ws;                              // 1 MiB (fallback)
    float* offpart = (float*)d_ws + 2 * BB * GG * NN;        // 12.58 MiB
    const size_t need = (size_t)(2 * BB * GG * NN + NCHUNK * 16 * BB * NN) * 4;

    if (ws_size >= need) {
        dq_conv_mfma<<<BB * HH * NCHUNK, 128, 0, stream>>>(
            x, dw_w, dw_b, off_w, wt_w, offpart);
        dq_sample_fused<<<BB * NN, 192, 0, stream>>>(
            x, offpart, off_b, wt_b, (float*)d_out);
    } else {
        dqshift_offsets_kernel<<<BB * NN / 4, 256, 0, stream>>>(
            x, dw_w, dw_b, off_w, off_b, wt_w, wt_b, ixiy);
        dqshift_sample_kernel<<<BB * NN, 256, 0, stream>>>(x, ixiy, (float*)d_out);
    }
}

// Round 6
// 105.937 us; speedup vs baseline: 1.1164x; 1.1164x over previous
//
#include <hip/hip_runtime.h>
#include <math.h>

// Problem constants: B=8, N=4096, C=768, H=W=64, GROUPS=4.
#define BB 8
#define CC 768
#define HH 64
#define WW 64
#define NN 4096
#define GG 4
#define NCHUNK 6
#define CHUNK 128   /* channels per A1 block */

typedef __attribute__((ext_vector_type(8))) short short8;
typedef __attribute__((ext_vector_type(4))) float f32x4;

__device__ __forceinline__ unsigned short f2bf(float f) {   // RNE float->bf16
    union { float f; unsigned u; } v; v.f = f;
    unsigned r = v.u + 0x7FFFu + ((v.u >> 16) & 1u);
    return (unsigned short)(r >> 16);
}

// tanh-form GELU approx: v * sigmoid(1.5957691*v*(1+0.044715*v^2)).
__device__ __forceinline__ float gelu_fast(float v) {
    const float z = 1.5957691216f * v * fmaf(0.044715f, v * v, 1.0f);
    return __fdividef(v, 1.0f + __expf(-z));
}

// ---------------------------------------------------------------------------
// A1: block = (b, row-pair hp, chunk of 128 ch), 128 threads (2 waves).
// Two output rows r0=2hp, r1=r0+1 share x rows {r0-1, r0, r1, r1+1}:
// 4 loads/column feed 2 output rows (-33% load insts vs 1-row blocks).
// Boundary rows handled by clamped pointers + zeroed tap weights (no selects).
// Per 16-col quarter: conv+GELU -> bf16 LDS (2 rows x 16 cols = 32 pos),
// then MFMA: D[pos][n] = [gelu|xc] x blockdiag(off_w, wt_w), 8 mfma/wave.
// Wave 0 covers r0's 16 positions, wave 1 covers r1's.
// ---------------------------------------------------------------------------
__global__ __launch_bounds__(128, 4) void dq_conv_mfma(
    const float* __restrict__ x,      // (B, N, C)
    const float* __restrict__ dw_w,   // (C, 9)
    const float* __restrict__ dw_b,   // (C,)
    const float* __restrict__ off_w,  // (8, C)
    const float* __restrict__ wt_w,   // (8, C)
    float* __restrict__ offpart)      // (NCHUNK, 16, B*N)
{
    __shared__ unsigned short gl[32][136];   // gelu bf16: [rowSel*16+colq][ch]
    __shared__ unsigned short xh[32][136];   // center x bf16
    const int t = threadIdx.x;
    const int lane = t & 63, wv = t >> 6;
    int bid = blockIdx.x;
    const int chunk = bid % NCHUNK; bid /= NCHUNK;
    const int hp = bid % (HH / 2);
    const int b = bid / (HH / 2);
    const int r0 = hp * 2, r1 = r0 + 1;
    const int c = chunk * CHUNK + t;

    // ---- B fragments: blockdiag [off_w ; wt_w], built once ----
    const int n = lane & 15, kg = lane >> 4;
    short8 bfrag[8];
#pragma unroll
    for (int kt = 0; kt < 8; ++kt) {
        const bool isOff = (kt < 4);
        const bool valid = isOff ? (n < 8) : (n >= 8);
        const int krow = isOff ? kt : kt - 4;
        const float* wp = isOff ? (off_w + (n < 8 ? n : 0) * CC)
                                : (wt_w + (n >= 8 ? n - 8 : 0) * CC);
        const float* src = wp + chunk * CHUNK + krow * 32 + kg * 8;
        short8 bf;
#pragma unroll
        for (int j = 0; j < 8; ++j) {
            const float v = valid ? src[j] : 0.f;
            bf[j] = (short)f2bf(v);
        }
        bfrag[kt] = bf;
    }

    float w9[9];
#pragma unroll
    for (int j = 0; j < 9; ++j) w9[j] = dw_w[c * 9 + j];
    const float bias = dw_b[c];
    const bool tv = (r0 > 0), bv = (r1 < HH - 1);
    const float wt0 = tv ? w9[0] : 0.f, wt1 = tv ? w9[1] : 0.f, wt2 = tv ? w9[2] : 0.f;
    const float wb0 = bv ? w9[6] : 0.f, wb1 = bv ? w9[7] : 0.f, wb2 = bv ? w9[8] : 0.f;

    const float* base = x + (size_t)b * NN * CC + c;
    const float* rA = base + (size_t)((tv ? r0 - 1 : 0) * WW) * CC;  // row r0-1 (clamped)
    const float* rB = base + (size_t)(r0 * WW) * CC;                 // row r0
    const float* rC = base + (size_t)(r1 * WW) * CC;                 // row r1
    const float* rD = base + (size_t)((bv ? r1 + 1 : r1) * WW) * CC; // row r1+1 (clamped)

    float cA[8], cB[8], cC[8], cD[8], nA[8], nB[8], nC[8], nD[8];
    float pA = 0.f, pB = 0.f, pC = 0.f, pD = 0.f;   // column w-1 carries

#pragma unroll
    for (int j = 0; j < 8; ++j) {
        cA[j] = rA[(size_t)j * CC];
        cB[j] = rB[(size_t)j * CC];
        cC[j] = rC[(size_t)j * CC];
        cD[j] = rD[(size_t)j * CC];
    }

    for (int wbk = 0; wbk < 8; ++wbk) {
        if (wbk < 7) {
#pragma unroll
            for (int j = 0; j < 8; ++j) {
                const size_t o = (size_t)(wbk * 8 + 8 + j) * CC;
                nA[j] = rA[o]; nB[j] = rB[o]; nC[j] = rC[o]; nD[j] = rD[o];
            }
        } else {
#pragma unroll
            for (int j = 0; j < 8; ++j) { nA[j] = 0.f; nB[j] = 0.f; nC[j] = 0.f; nD[j] = 0.f; }
        }
#pragma unroll
        for (int j = 0; j < 8; ++j) {
            const float lA = j ? cA[j - 1] : pA;
            const float lB = j ? cB[j - 1] : pB;
            const float lC = j ? cC[j - 1] : pC;
            const float lD = j ? cD[j - 1] : pD;
            const float rAv = (j == 7) ? nA[0] : cA[j + 1];
            const float rBv = (j == 7) ? nB[0] : cB[j + 1];
            const float rCv = (j == 7) ? nC[0] : cC[j + 1];
            const float rDv = (j == 7) ? nD[0] : cD[j + 1];
            // output row r0: taps rows {A,B,C}; top weights masked at h=0
            const float conv0 = lA * wt0 + cA[j] * wt1 + rAv * wt2
                              + lB * w9[3] + cB[j] * w9[4] + rBv * w9[5]
                              + lC * w9[6] + cC[j] * w9[7] + rCv * w9[8];
            // output row r1: taps rows {B,C,D}; bottom weights masked at h=63
            const float conv1 = lB * w9[0] + cB[j] * w9[1] + rBv * w9[2]
                              + lC * w9[3] + cC[j] * w9[4] + rCv * w9[5]
                              + lD * wb0 + cD[j] * wb1 + rDv * wb2;
            const int colq = (wbk & 1) * 8 + j;     // column within quarter
            gl[colq][t]      = f2bf(gelu_fast(conv0 + bias));
            gl[16 + colq][t] = f2bf(gelu_fast(conv1 + bias));
            xh[colq][t]      = f2bf(cB[j]);
            xh[16 + colq][t] = f2bf(cC[j]);
        }
        pA = cA[7]; pB = cB[7]; pC = cC[7]; pD = cD[7];
#pragma unroll
        for (int j = 0; j < 8; ++j) { cA[j] = nA[j]; cB[j] = nB[j]; cC[j] = nC[j]; cD[j] = nD[j]; }

        if (wbk & 1) {                   // end of 16-col quarter q
            const int q = wbk >> 1;
            __syncthreads();
            f32x4 acc = {0.f, 0.f, 0.f, 0.f};
            const int arow = wv * 16 + n;
#pragma unroll
            for (int kt = 0; kt < 4; ++kt) {
                const short8 a = *(const short8*)&gl[arow][kt * 32 + kg * 8];
                acc = __builtin_amdgcn_mfma_f32_16x16x32_bf16(a, bfrag[kt], acc, 0, 0, 0);
            }
#pragma unroll
            for (int kt = 0; kt < 4; ++kt) {
                const short8 a = *(const short8*)&xh[arow][kt * 32 + kg * 8];
                acc = __builtin_amdgcn_mfma_f32_16x16x32_bf16(a, bfrag[4 + kt], acc, 0, 0, 0);
            }
            // D: col n = output, rows kg*4..+3 = 4 consecutive columns
            const int r = wv ? r1 : r0;
            const size_t gpos = (size_t)(b * NN) + r * WW + q * 16 + kg * 4;
            float4 st; st.x = acc[0]; st.y = acc[1]; st.z = acc[2]; st.w = acc[3];
            *(float4*)&offpart[((size_t)(chunk * 16 + n)) * (BB * NN) + gpos] = st;
            if (wbk < 7) __syncthreads();
        }
    }
}

// ---------------------------------------------------------------------------
// Combine (coalesced): sum 6 chunk partials, sigmoid gate, shift, clip.
// thread: o = t>>5 (0..7), pos = blk*32 + (t&31)  -> gpos-coalesced reads.
// ---------------------------------------------------------------------------
__global__ __launch_bounds__(256) void dq_combine(
    const float* __restrict__ offpart,  // (NCHUNK, 16, B*N)
    const float* __restrict__ off_b,
    const float* __restrict__ wt_b,
    float* __restrict__ ixiy)           // (2, B*G, N)
{
    const int t = threadIdx.x;
    const int o = t >> 5;
    const int gpos = blockIdx.x * 32 + (t & 31);
    const int b = gpos >> 12;
    const int hw = gpos & 4095;
    const int h = hw >> 6, w = hw & 63;

    float so = 0.f, sw = 0.f;
#pragma unroll
    for (int ch = 0; ch < NCHUNK; ++ch) {
        so += offpart[((size_t)(ch * 16 + o)) * (BB * NN) + gpos];
        sw += offpart[((size_t)(ch * 16 + 8 + o)) * (BB * NN) + gpos];
    }
    const float sig = 1.f / (1.f + __expf(-(sw + wt_b[o])));
    const float val = (so + off_b[o]) * sig;

    if (o < 4) {
        const float shx = (o == 2) ? -1.f : ((o == 3) ? 1.f : 0.f);
        const float ix = fminf(fmaxf((float)w + val + shx, 0.f), (float)(WW - 1));
        ixiy[(b * GG + o) * NN + hw] = ix;
    } else {
        const int g = o - 4;
        const float shy = (g == 0) ? -1.f : ((g == 1) ? 1.f : 0.f);
        const float iy = fminf(fmaxf((float)h + val + shy, 0.f), (float)(HH - 1));
        ixiy[BB * GG * NN + (b * GG + g) * NN + hw] = iy;
    }
}

// ---------------------------------------------------------------------------
// B: bilinear border sampling, float4-vectorized. 192 threads, 4 ch/thread.
// 8 coord loads per block (broadcast via LDS), 4x fewer mem insts than scalar.
// ---------------------------------------------------------------------------
__global__ __launch_bounds__(192) void dq_sample_vec(
    const float* __restrict__ x,        // (B, N, C)
    const float* __restrict__ ixiy,     // (2, B*G, N)
    float* __restrict__ out)            // (B, N, C)
{
    __shared__ float ixy[8];            // ix[4], iy[4]
    const int t = threadIdx.x;
    const int p = blockIdx.x;           // over B*N
    const int b = p >> 12;
    const int hw = p & 4095;

    if (t < 8) {
        const int g = t & 3;
        const int plane = (t >> 2) * (BB * GG * NN);
        ixy[t] = ixiy[plane + (b * GG + g) * NN + hw];
    }
    __syncthreads();

    const int g = t / 48;               // 48 threads x 4ch = 192 ch per group
    const float ix = ixy[g], iy = ixy[4 + g];
    const float x0f = floorf(ix), y0f = floorf(iy);
    const float wx = ix - x0f, wy = iy - y0f;
    const int x0 = (int)x0f, y0 = (int)y0f;
    const int x1 = min(x0 + 1, WW - 1), y1 = min(y0 + 1, HH - 1);
    const int c4 = t * 4;
    const float* xb = x + (size_t)b * NN * CC;
    const float4 v00 = *(const float4*)(xb + (size_t)(y0 * WW + x0) * CC + c4);
    const float4 v01 = *(const float4*)(xb + (size_t)(y0 * WW + x1) * CC + c4);
    const float4 v10 = *(const float4*)(xb + (size_t)(y1 * WW + x0) * CC + c4);
    const float4 v11 = *(const float4*)(xb + (size_t)(y1 * WW + x1) * CC + c4);
    const float w00 = (1.f - wx) * (1.f - wy), w01 = wx * (1.f - wy);
    const float w10 = (1.f - wx) * wy,         w11 = wx * wy;
    float4 r;
    r.x = v00.x * w00 + v01.x * w01 + v10.x * w10 + v11.x * w11;
    r.y = v00.y * w00 + v01.y * w01 + v10.y * w10 + v11.y * w11;
    r.z = v00.z * w00 + v01.z * w01 + v10.z * w10 + v11.z * w11;
    r.w = v00.w * w00 + v01.w * w01 + v10.w * w10 + v11.w * w11;
    *(float4*)(out + (size_t)p * CC + c4) = r;
}

// ---------------------------------------------------------------------------
// Fallback (small ws): round-1 fused offsets kernel + scalar sampler.
// ---------------------------------------------------------------------------
__global__ __launch_bounds__(256) void dqshift_offsets_kernel(
    const float* __restrict__ x, const float* __restrict__ dw_w,
    const float* __restrict__ dw_b, const float* __restrict__ off_w,
    const float* __restrict__ off_b, const float* __restrict__ wt_w,
    const float* __restrict__ wt_b, float* __restrict__ ixiy)
{
    const int wave = threadIdx.x >> 6;
    const int lane = threadIdx.x & 63;
    const int p = blockIdx.x * 4 + wave;
    const int b = p >> 12;
    const int hw = p & 4095;
    const int h = hw >> 6;
    const int w = hw & 63;
    const float* xb = x + (size_t)b * NN * CC;
    float accO[8], accW[8];
#pragma unroll
    for (int o = 0; o < 8; ++o) { accO[o] = 0.f; accW[o] = 0.f; }
    for (int k = 0; k < CC / 64; ++k) {
        const int c = lane + (k << 6);
        float conv = 0.f, xc = 0.f;
#pragma unroll
        for (int dy = -1; dy <= 1; ++dy) {
            const int hh = h + dy;
            const bool vy = (hh >= 0) && (hh < HH);
#pragma unroll
            for (int dx = -1; dx <= 1; ++dx) {
                const int ww = w + dx;
                const bool vv = vy && (ww >= 0) && (ww < WW);
                const float tt = vv ? xb[(size_t)(hh * WW + ww) * CC + c] : 0.f;
                if (dy == 0 && dx == 0) xc = tt;
                conv = fmaf(tt, dw_w[c * 9 + (dy + 1) * 3 + (dx + 1)], conv);
            }
        }
        const float gv = conv + dw_b[c];
        const float gle = 0.5f * gv * (1.0f + erff(gv * 0.70710678118654752f));
#pragma unroll
        for (int o = 0; o < 8; ++o) {
            accO[o] = fmaf(gle, off_w[o * CC + c], accO[o]);
            accW[o] = fmaf(xc, wt_w[o * CC + c], accW[o]);
        }
    }
#pragma unroll
    for (int o = 0; o < 8; ++o) {
#pragma unroll
        for (int s = 32; s > 0; s >>= 1) {
            accO[o] += __shfl_xor(accO[o], s, 64);
            accW[o] += __shfl_xor(accW[o], s, 64);
        }
    }
    if (lane == 0) {
        const float shx[4] = {0.f, 0.f, -1.f, 1.f};
        const float shy[4] = {-1.f, 1.f, 0.f, 0.f};
#pragma unroll
        for (int g = 0; g < 4; ++g) {
            const float sx = 1.f / (1.f + expf(-(accW[g] + wt_b[g])));
            const float sy = 1.f / (1.f + expf(-(accW[4 + g] + wt_b[4 + g])));
            const float ox = (accO[g] + off_b[g]) * sx + shx[g];
            const float oy = (accO[4 + g] + off_b[4 + g]) * sy + shy[g];
            const float ix = fminf(fmaxf((float)w + ox, 0.f), (float)(WW - 1));
            const float iy = fminf(fmaxf((float)h + oy, 0.f), (float)(HH - 1));
            const int idx = (b * GG + g) * NN + hw;
            ixiy[idx] = ix;
            ixiy[BB * GG * NN + idx] = iy;
        }
    }
}

__global__ __launch_bounds__(256) void dqshift_sample_kernel(
    const float* __restrict__ x,
    const float* __restrict__ ixiy,
    float* __restrict__ out)
{
    const int p = blockIdx.x;
    const int b = p >> 12;
    const int hw = p & 4095;
    const float* xb = x + (size_t)b * NN * CC;
    float* ob = out + (size_t)p * CC;

#pragma unroll
    for (int k = 0; k < 3; ++k) {
        const int c = threadIdx.x + (k << 8);
        const int g = c / (CC / GG);
        const int idx = (b * GG + g) * NN + hw;
        const float ix = ixiy[idx];
        const float iy = ixiy[BB * GG * NN + idx];
        const float x0f = floorf(ix);
        const float y0f = floorf(iy);
        const float wx = ix - x0f;
        const float wy = iy - y0f;
        const int x0 = (int)x0f;
        const int y0 = (int)y0f;
        const int x1 = min(x0 + 1, WW - 1);
        const int y1 = min(y0 + 1, HH - 1);
        const float* r0 = xb + (size_t)(y0 * WW) * CC + c;
        const float* r1 = xb + (size_t)(y1 * WW) * CC + c;
        const float v00 = r0[(size_t)x0 * CC];
        const float v01 = r0[(size_t)x1 * CC];
        const float v10 = r1[(size_t)x0 * CC];
        const float v11 = r1[(size_t)x1 * CC];
        ob[c] = v00 * (1.f - wx) * (1.f - wy) + v01 * wx * (1.f - wy)
              + v10 * (1.f - wx) * wy + v11 * wx * wy;
    }
}

extern "C" void kernel_launch(void* const* d_in, const int* in_sizes, int n_in,
                              void* d_out, int out_size, void* d_ws, size_t ws_size,
                              hipStream_t stream) {
    const float* x     = (const float*)d_in[0];
    const float* dw_w  = (const float*)d_in[1];
    const float* dw_b  = (const float*)d_in[2];
    const float* off_w = (const float*)d_in[3];
    const float* off_b = (const float*)d_in[4];
    const float* wt_w  = (const float*)d_in[5];
    const float* wt_b  = (const float*)d_in[6];

    float* ixiy = (float*)d_ws;                              // 1 MiB
    float* offpart = (float*)d_ws + 2 * BB * GG * NN;        // 12.58 MiB
    const size_t need = (size_t)(2 * BB * GG * NN + NCHUNK * 16 * BB * NN) * 4;

    if (ws_size >= need) {
        dq_conv_mfma<<<BB * (HH / 2) * NCHUNK, 128, 0, stream>>>(
            x, dw_w, dw_b, off_w, wt_w, offpart);
        dq_combine<<<BB * NN / 32, 256, 0, stream>>>(
            offpart, off_b, wt_b, ixiy);
        dq_sample_vec<<<BB * NN, 192, 0, stream>>>(
            x, ixiy, (float*)d_out);
    } else {
        dqshift_offsets_kernel<<<BB * NN / 4, 256, 0, stream>>>(
            x, dw_w, dw_b, off_w, off_b, wt_w, wt_b, ixiy);
        dqshift_sample_kernel<<<BB * NN, 256, 0, stream>>>(x, ixiy, (float*)d_out);
    }
}

// Round 7
// 100.161 us; speedup vs baseline: 1.1807x; 1.0577x over previous
//
#include <hip/hip_runtime.h>
#include <math.h>

// Problem constants: B=8, N=4096, C=768, H=W=64, GROUPS=4.
#define BB 8
#define CC 768
#define HH 64
#define WW 64
#define NN 4096
#define GG 4
#define NCHUNK 6
#define CHUNK 128   /* channels per A1 block */

typedef __attribute__((ext_vector_type(8))) short short8;
typedef __attribute__((ext_vector_type(4))) float f32x4;

__device__ __forceinline__ unsigned short f2bf(float f) {   // RNE float->bf16
    union { float f; unsigned u; } v; v.f = f;
    unsigned r = v.u + 0x7FFFu + ((v.u >> 16) & 1u);
    return (unsigned short)(r >> 16);
}

// tanh-form GELU approx: v * sigmoid(1.5957691*v*(1+0.044715*v^2)).
__device__ __forceinline__ float gelu_fast(float v) {
    const float z = 1.5957691216f * v * fmaf(0.044715f, v * v, 1.0f);
    return __fdividef(v, 1.0f + __expf(-z));
}

// ---------------------------------------------------------------------------
// A1: block = (b, row-pair hp, column-half ch2, chunk of 128 ch), 128 thr.
// Grid 3072 (= 12 blocks/CU demand; LDS 17.4KB allows 9 -> ~18 waves/CU,
// double round-6's 6-blocks/CU grid limit).
// Two output rows r0=2hp, r1=r0+1 share x rows {r0-1,r0,r1,r1+1}; 32 output
// columns cstart..cstart+31 with halo cols cstart-1 / cstart+32.
// Boundary rows via clamped pointers + zeroed tap weights.
// Per 16-col quarter: conv+GELU -> bf16 LDS (2 rows x 16 cols = 32 pos),
// MFMA: D[pos][n] = [gelu|xc] x blockdiag(off_w, wt_w), 8 mfma/wave.
// ---------------------------------------------------------------------------
__global__ __launch_bounds__(128, 4) void dq_conv_mfma(
    const float* __restrict__ x,      // (B, N, C)
    const float* __restrict__ dw_w,   // (C, 9)
    const float* __restrict__ dw_b,   // (C,)
    const float* __restrict__ off_w,  // (8, C)
    const float* __restrict__ wt_w,   // (8, C)
    float* __restrict__ offpart)      // (NCHUNK, 16, B*N)
{
    __shared__ unsigned short gl[32][136];   // gelu bf16: [rowSel*16+colq][ch]
    __shared__ unsigned short xh[32][136];   // center x bf16
    const int t = threadIdx.x;
    const int lane = t & 63, wv = t >> 6;
    int bid = blockIdx.x;
    const int chunk = bid % NCHUNK; bid /= NCHUNK;
    const int ch2 = bid & 1; bid >>= 1;
    const int hp = bid % (HH / 2);
    const int b = bid / (HH / 2);
    const int r0 = hp * 2, r1 = r0 + 1;
    const int cstart = ch2 * 32;
    const int c = chunk * CHUNK + t;

    // ---- B fragments: blockdiag [off_w ; wt_w], built once ----
    const int n = lane & 15, kg = lane >> 4;
    short8 bfrag[8];
#pragma unroll
    for (int kt = 0; kt < 8; ++kt) {
        const bool isOff = (kt < 4);
        const bool valid = isOff ? (n < 8) : (n >= 8);
        const int krow = isOff ? kt : kt - 4;
        const float* wp = isOff ? (off_w + (n < 8 ? n : 0) * CC)
                                : (wt_w + (n >= 8 ? n - 8 : 0) * CC);
        const float* src = wp + chunk * CHUNK + krow * 32 + kg * 8;
        short8 bf;
#pragma unroll
        for (int j = 0; j < 8; ++j) {
            const float v = valid ? src[j] : 0.f;
            bf[j] = (short)f2bf(v);
        }
        bfrag[kt] = bf;
    }

    float w9[9];
#pragma unroll
    for (int j = 0; j < 9; ++j) w9[j] = dw_w[c * 9 + j];
    const float bias = dw_b[c];
    const bool tv = (r0 > 0), bv = (r1 < HH - 1);
    const float wt0 = tv ? w9[0] : 0.f, wt1 = tv ? w9[1] : 0.f, wt2 = tv ? w9[2] : 0.f;
    const float wb0 = bv ? w9[6] : 0.f, wb1 = bv ? w9[7] : 0.f, wb2 = bv ? w9[8] : 0.f;

    const float* base = x + (size_t)b * NN * CC + c;
    const float* rA = base + (size_t)((tv ? r0 - 1 : 0) * WW) * CC;  // r0-1 (clamped)
    const float* rB = base + (size_t)(r0 * WW) * CC;                 // r0
    const float* rC = base + (size_t)(r1 * WW) * CC;                 // r1
    const float* rD = base + (size_t)((bv ? r1 + 1 : r1) * WW) * CC; // r1+1 (clamped)

    float cA[8], cB[8], cC[8], cD[8], nA[8], nB[8], nC[8], nD[8];
    // left-halo carry (col cstart-1) and right-halo tail (col cstart+32)
    float pA, pB, pC, pD, tA, tB, tC, tD;
    if (cstart > 0) {
        const size_t o = (size_t)(cstart - 1) * CC;
        pA = rA[o]; pB = rB[o]; pC = rC[o]; pD = rD[o];
    } else { pA = 0.f; pB = 0.f; pC = 0.f; pD = 0.f; }
    if (cstart + 32 < WW) {
        const size_t o = (size_t)(cstart + 32) * CC;
        tA = rA[o]; tB = rB[o]; tC = rC[o]; tD = rD[o];
    } else { tA = 0.f; tB = 0.f; tC = 0.f; tD = 0.f; }

#pragma unroll
    for (int j = 0; j < 8; ++j) {
        const size_t o = (size_t)(cstart + j) * CC;
        cA[j] = rA[o]; cB[j] = rB[o]; cC[j] = rC[o]; cD[j] = rD[o];
    }

    for (int wbk = 0; wbk < 4; ++wbk) {
        if (wbk < 3) {
#pragma unroll
            for (int j = 0; j < 8; ++j) {
                const size_t o = (size_t)(cstart + wbk * 8 + 8 + j) * CC;
                nA[j] = rA[o]; nB[j] = rB[o]; nC[j] = rC[o]; nD[j] = rD[o];
            }
        } else {
            nA[0] = tA; nB[0] = tB; nC[0] = tC; nD[0] = tD;
#pragma unroll
            for (int j = 1; j < 8; ++j) { nA[j] = 0.f; nB[j] = 0.f; nC[j] = 0.f; nD[j] = 0.f; }
        }
#pragma unroll
        for (int j = 0; j < 8; ++j) {
            const float lA = j ? cA[j - 1] : pA;
            const float lB = j ? cB[j - 1] : pB;
            const float lC = j ? cC[j - 1] : pC;
            const float lD = j ? cD[j - 1] : pD;
            const float rAv = (j == 7) ? nA[0] : cA[j + 1];
            const float rBv = (j == 7) ? nB[0] : cB[j + 1];
            const float rCv = (j == 7) ? nC[0] : cC[j + 1];
            const float rDv = (j == 7) ? nD[0] : cD[j + 1];
            // output row r0: taps rows {A,B,C}; top weights masked at h=0
            const float conv0 = lA * wt0 + cA[j] * wt1 + rAv * wt2
                              + lB * w9[3] + cB[j] * w9[4] + rBv * w9[5]
                              + lC * w9[6] + cC[j] * w9[7] + rCv * w9[8];
            // output row r1: taps rows {B,C,D}; bottom weights masked at h=63
            const float conv1 = lB * w9[0] + cB[j] * w9[1] + rBv * w9[2]
                              + lC * w9[3] + cC[j] * w9[4] + rCv * w9[5]
                              + lD * wb0 + cD[j] * wb1 + rDv * wb2;
            const int colq = (wbk & 1) * 8 + j;     // column within quarter
            gl[colq][t]      = f2bf(gelu_fast(conv0 + bias));
            gl[16 + colq][t] = f2bf(gelu_fast(conv1 + bias));
            xh[colq][t]      = f2bf(cB[j]);
            xh[16 + colq][t] = f2bf(cC[j]);
        }
        pA = cA[7]; pB = cB[7]; pC = cC[7]; pD = cD[7];
#pragma unroll
        for (int j = 0; j < 8; ++j) { cA[j] = nA[j]; cB[j] = nB[j]; cC[j] = nC[j]; cD[j] = nD[j]; }

        if (wbk & 1) {                   // end of 16-col quarter q
            const int q = wbk >> 1;
            __syncthreads();
            f32x4 acc = {0.f, 0.f, 0.f, 0.f};
            const int arow = wv * 16 + n;
#pragma unroll
            for (int kt = 0; kt < 4; ++kt) {
                const short8 a = *(const short8*)&gl[arow][kt * 32 + kg * 8];
                acc = __builtin_amdgcn_mfma_f32_16x16x32_bf16(a, bfrag[kt], acc, 0, 0, 0);
            }
#pragma unroll
            for (int kt = 0; kt < 4; ++kt) {
                const short8 a = *(const short8*)&xh[arow][kt * 32 + kg * 8];
                acc = __builtin_amdgcn_mfma_f32_16x16x32_bf16(a, bfrag[4 + kt], acc, 0, 0, 0);
            }
            // D: col n = output, rows kg*4..+3 = 4 consecutive columns
            const int r = wv ? r1 : r0;
            const size_t gpos = (size_t)(b * NN) + r * WW + cstart + q * 16 + kg * 4;
            float4 st; st.x = acc[0]; st.y = acc[1]; st.z = acc[2]; st.w = acc[3];
            *(float4*)&offpart[((size_t)(chunk * 16 + n)) * (BB * NN) + gpos] = st;
            if (wbk < 3) __syncthreads();
        }
    }
}

// ---------------------------------------------------------------------------
// Combine (coalesced): sum 6 chunk partials, sigmoid gate, shift, clip.
// thread: o = t>>5 (0..7), pos = blk*32 + (t&31)  -> gpos-coalesced reads.
// ---------------------------------------------------------------------------
__global__ __launch_bounds__(256) void dq_combine(
    const float* __restrict__ offpart,  // (NCHUNK, 16, B*N)
    const float* __restrict__ off_b,
    const float* __restrict__ wt_b,
    float* __restrict__ ixiy)           // (2, B*G, N)
{
    const int t = threadIdx.x;
    const int o = t >> 5;
    const int gpos = blockIdx.x * 32 + (t & 31);
    const int b = gpos >> 12;
    const int hw = gpos & 4095;
    const int h = hw >> 6, w = hw & 63;

    float so = 0.f, sw = 0.f;
#pragma unroll
    for (int ch = 0; ch < NCHUNK; ++ch) {
        so += offpart[((size_t)(ch * 16 + o)) * (BB * NN) + gpos];
        sw += offpart[((size_t)(ch * 16 + 8 + o)) * (BB * NN) + gpos];
    }
    const float sig = 1.f / (1.f + __expf(-(sw + wt_b[o])));
    const float val = (so + off_b[o]) * sig;

    if (o < 4) {
        const float shx = (o == 2) ? -1.f : ((o == 3) ? 1.f : 0.f);
        const float ix = fminf(fmaxf((float)w + val + shx, 0.f), (float)(WW - 1));
        ixiy[(b * GG + o) * NN + hw] = ix;
    } else {
        const int g = o - 4;
        const float shy = (g == 0) ? -1.f : ((g == 1) ? 1.f : 0.f);
        const float iy = fminf(fmaxf((float)h + val + shy, 0.f), (float)(HH - 1));
        ixiy[BB * GG * NN + (b * GG + g) * NN + hw] = iy;
    }
}

// ---------------------------------------------------------------------------
// B: bilinear border sampling, float4-vectorized, XCD-swizzled (T1).
// 192 threads, 4 ch/thread; 8 coord loads per block broadcast via LDS.
// ---------------------------------------------------------------------------
__global__ __launch_bounds__(192) void dq_sample_vec(
    const float* __restrict__ x,        // (B, N, C)
    const float* __restrict__ ixiy,     // (2, B*G, N)
    float* __restrict__ out)            // (B, N, C)
{
    __shared__ float ixy[8];            // ix[4], iy[4]
    const int t = threadIdx.x;
    // XCD-aware bijective swizzle: 32768 blocks % 8 XCDs == 0; each XCD walks
    // a contiguous chunk of positions -> bilinear rows stay L2-resident.
    const int p = (blockIdx.x & 7) * (BB * NN / 8) + (blockIdx.x >> 3);
    const int b = p >> 12;
    const int hw = p & 4095;

    if (t < 8) {
        const int g = t & 3;
        const int plane = (t >> 2) * (BB * GG * NN);
        ixy[t] = ixiy[plane + (b * GG + g) * NN + hw];
    }
    __syncthreads();

    const int g = t / 48;               // 48 threads x 4ch = 192 ch per group
    const float ix = ixy[g], iy = ixy[4 + g];
    const float x0f = floorf(ix), y0f = floorf(iy);
    const float wx = ix - x0f, wy = iy - y0f;
    const int x0 = (int)x0f, y0 = (int)y0f;
    const int x1 = min(x0 + 1, WW - 1), y1 = min(y0 + 1, HH - 1);
    const int c4 = t * 4;
    const float* xb = x + (size_t)b * NN * CC;
    const float4 v00 = *(const float4*)(xb + (size_t)(y0 * WW + x0) * CC + c4);
    const float4 v01 = *(const float4*)(xb + (size_t)(y0 * WW + x1) * CC + c4);
    const float4 v10 = *(const float4*)(xb + (size_t)(y1 * WW + x0) * CC + c4);
    const float4 v11 = *(const float4*)(xb + (size_t)(y1 * WW + x1) * CC + c4);
    const float w00 = (1.f - wx) * (1.f - wy), w01 = wx * (1.f - wy);
    const float w10 = (1.f - wx) * wy,         w11 = wx * wy;
    float4 r;
    r.x = v00.x * w00 + v01.x * w01 + v10.x * w10 + v11.x * w11;
    r.y = v00.y * w00 + v01.y * w01 + v10.y * w10 + v11.y * w11;
    r.z = v00.z * w00 + v01.z * w01 + v10.z * w10 + v11.z * w11;
    r.w = v00.w * w00 + v01.w * w01 + v10.w * w10 + v11.w * w11;
    *(float4*)(out + (size_t)p * CC + c4) = r;
}

// ---------------------------------------------------------------------------
// Fallback (small ws): round-1 fused offsets kernel + scalar sampler.
// ---------------------------------------------------------------------------
__global__ __launch_bounds__(256) void dqshift_offsets_kernel(
    const float* __restrict__ x, const float* __restrict__ dw_w,
    const float* __restrict__ dw_b, const float* __restrict__ off_w,
    const float* __restrict__ off_b, const float* __restrict__ wt_w,
    const float* __restrict__ wt_b, float* __restrict__ ixiy)
{
    const int wave = threadIdx.x >> 6;
    const int lane = threadIdx.x & 63;
    const int p = blockIdx.x * 4 + wave;
    const int b = p >> 12;
    const int hw = p & 4095;
    const int h = hw >> 6;
    const int w = hw & 63;
    const float* xb = x + (size_t)b * NN * CC;
    float accO[8], accW[8];
#pragma unroll
    for (int o = 0; o < 8; ++o) { accO[o] = 0.f; accW[o] = 0.f; }
    for (int k = 0; k < CC / 64; ++k) {
        const int c = lane + (k << 6);
        float conv = 0.f, xc = 0.f;
#pragma unroll
        for (int dy = -1; dy <= 1; ++dy) {
            const int hh = h + dy;
            const bool vy = (hh >= 0) && (hh < HH);
#pragma unroll
            for (int dx = -1; dx <= 1; ++dx) {
                const int ww = w + dx;
                const bool vv = vy && (ww >= 0) && (ww < WW);
                const float tt = vv ? xb[(size_t)(hh * WW + ww) * CC + c] : 0.f;
                if (dy == 0 && dx == 0) xc = tt;
                conv = fmaf(tt, dw_w[c * 9 + (dy + 1) * 3 + (dx + 1)], conv);
            }
        }
        const float gv = conv + dw_b[c];
        const float gle = 0.5f * gv * (1.0f + erff(gv * 0.70710678118654752f));
#pragma unroll
        for (int o = 0; o < 8; ++o) {
            accO[o] = fmaf(gle, off_w[o * CC + c], accO[o]);
            accW[o] = fmaf(xc, wt_w[o * CC + c], accW[o]);
        }
    }
#pragma unroll
    for (int o = 0; o < 8; ++o) {
#pragma unroll
        for (int s = 32; s > 0; s >>= 1) {
            accO[o] += __shfl_xor(accO[o], s, 64);
            accW[o] += __shfl_xor(accW[o], s, 64);
        }
    }
    if (lane == 0) {
        const float shx[4] = {0.f, 0.f, -1.f, 1.f};
        const float shy[4] = {-1.f, 1.f, 0.f, 0.f};
#pragma unroll
        for (int g = 0; g < 4; ++g) {
            const float sx = 1.f / (1.f + expf(-(accW[g] + wt_b[g])));
            const float sy = 1.f / (1.f + expf(-(accW[4 + g] + wt_b[4 + g])));
            const float ox = (accO[g] + off_b[g]) * sx + shx[g];
            const float oy = (accO[4 + g] + off_b[4 + g]) * sy + shy[g];
            const float ix = fminf(fmaxf((float)w + ox, 0.f), (float)(WW - 1));
            const float iy = fminf(fmaxf((float)h + oy, 0.f), (float)(HH - 1));
            const int idx = (b * GG + g) * NN + hw;
            ixiy[idx] = ix;
            ixiy[BB * GG * NN + idx] = iy;
        }
    }
}

__global__ __launch_bounds__(256) void dqshift_sample_kernel(
    const float* __restrict__ x,
    const float* __restrict__ ixiy,
    float* __restrict__ out)
{
    const int p = blockIdx.x;
    const int b = p >> 12;
    const int hw = p & 4095;
    const float* xb = x + (size_t)b * NN * CC;
    float* ob = out + (size_t)p * CC;

#pragma unroll
    for (int k = 0; k < 3; ++k) {
        const int c = threadIdx.x + (k << 8);
        const int g = c / (CC / GG);
        const int idx = (b * GG + g) * NN + hw;
        const float ix = ixiy[idx];
        const float iy = ixiy[BB * GG * NN + idx];
        const float x0f = floorf(ix);
        const float y0f = floorf(iy);
        const float wx = ix - x0f;
        const float wy = iy - y0f;
        const int x0 = (int)x0f;
        const int y0 = (int)y0f;
        const int x1 = min(x0 + 1, WW - 1);
        const int y1 = min(y0 + 1, HH - 1);
        const float* r0 = xb + (size_t)(y0 * WW) * CC + c;
        const float* r1 = xb + (size_t)(y1 * WW) * CC + c;
        const float v00 = r0[(size_t)x0 * CC];
        const float v01 = r0[(size_t)x1 * CC];
        const float v10 = r1[(size_t)x0 * CC];
        const float v11 = r1[(size_t)x1 * CC];
        ob[c] = v00 * (1.f - wx) * (1.f - wy) + v01 * wx * (1.f - wy)
              + v10 * (1.f - wx) * wy + v11 * wx * wy;
    }
}

extern "C" void kernel_launch(void* const* d_in, const int* in_sizes, int n_in,
                              void* d_out, int out_size, void* d_ws, size_t ws_size,
                              hipStream_t stream) {
    const float* x     = (const float*)d_in[0];
    const float* dw_w  = (const float*)d_in[1];
    const float* dw_b  = (const float*)d_in[2];
    const float* off_w = (const float*)d_in[3];
    const float* off_b = (const float*)d_in[4];
    const float* wt_w  = (const float*)d_in[5];
    const float* wt_b  = (const float*)d_in[6];

    float* ixiy = (float*)d_ws;                              // 1 MiB
    float* offpart = (float*)d_ws + 2 * BB * GG * NN;        // 12.58 MiB
    const size_t need = (size_t)(2 * BB * GG * NN + NCHUNK * 16 * BB * NN) * 4;

    if (ws_size >= need) {
        dq_conv_mfma<<<BB * (HH / 2) * 2 * NCHUNK, 128, 0, stream>>>(
            x, dw_w, dw_b, off_w, wt_w, offpart);
        dq_combine<<<BB * NN / 32, 256, 0, stream>>>(
            offpart, off_b, wt_b, ixiy);
        dq_sample_vec<<<BB * NN, 192, 0, stream>>>(
            x, ixiy, (float*)d_out);
    } else {
        dqshift_offsets_kernel<<<BB * NN / 4, 256, 0, stream>>>(
            x, dw_w, dw_b, off_w, off_b, wt_w, wt_b, ixiy);
        dqshift_sample_kernel<<<BB * NN, 256, 0, stream>>>(x, ixiy, (float*)d_out);
    }
}

// Round 8
// 94.826 us; speedup vs baseline: 1.2472x; 1.0563x over previous
//
#include <hip/hip_runtime.h>
#include <math.h>

// Problem constants: B=8, N=4096, C=768, H=W=64, GROUPS=4.
#define BB 8
#define CC 768
#define HH 64
#define WW 64
#define NN 4096
#define GG 4
#define NCHUNK 6
#define CHUNK 128   /* channels per A1 block */

typedef __attribute__((ext_vector_type(8))) short short8;
typedef __attribute__((ext_vector_type(4))) float f32x4;

__device__ __forceinline__ unsigned short f2bf(float f) {   // RNE float->bf16
    union { float f; unsigned u; } v; v.f = f;
    unsigned r = v.u + 0x7FFFu + ((v.u >> 16) & 1u);
    return (unsigned short)(r >> 16);
}

// tanh-form GELU approx: v * sigmoid(1.5957691*v*(1+0.044715*v^2)).
__device__ __forceinline__ float gelu_fast(float v) {
    const float z = 1.5957691216f * v * fmaf(0.044715f, v * v, 1.0f);
    return __fdividef(v, 1.0f + __expf(-z));
}

// ---------------------------------------------------------------------------
// A1 (round-6 structure + register-accumulated stores):
// block = (b, row-pair hp, chunk of 128 ch), 128 threads (2 waves), grid 1536.
// Two output rows r0=2hp, r1=r0+1 share x rows {r0-1,r0,r1,r1+1}: 4 loads
// per column feed 2 output rows. Boundary rows via clamped pointers + zeroed
// tap weights. Per 16-col quarter: conv+GELU -> bf16 LDS (2 rows x 16 cols),
// MFMA D[pos][n] = [gelu|xc] x blockdiag(off_w, wt_w), 8 mfma/wave -> accq[q].
// ALL stores deferred to block end: each plane's 64-col row (256 B) is written
// back-to-back -> full-line L2 writes (round 7 showed split/interleaved
// stores cost 2-3x write amplification).
// ---------------------------------------------------------------------------
__global__ __launch_bounds__(128, 4) void dq_conv_mfma(
    const float* __restrict__ x,      // (B, N, C)
    const float* __restrict__ dw_w,   // (C, 9)
    const float* __restrict__ dw_b,   // (C,)
    const float* __restrict__ off_w,  // (8, C)
    const float* __restrict__ wt_w,   // (8, C)
    float* __restrict__ offpart)      // (NCHUNK, 16, B*N)
{
    __shared__ unsigned short gl[32][136];   // gelu bf16: [rowSel*16+colq][ch]
    __shared__ unsigned short xh[32][136];   // center x bf16
    const int t = threadIdx.x;
    const int lane = t & 63, wv = t >> 6;
    int bid = blockIdx.x;
    const int chunk = bid % NCHUNK; bid /= NCHUNK;
    const int hp = bid % (HH / 2);
    const int b = bid / (HH / 2);
    const int r0 = hp * 2, r1 = r0 + 1;
    const int c = chunk * CHUNK + t;

    // ---- B fragments: blockdiag [off_w ; wt_w], built once ----
    const int n = lane & 15, kg = lane >> 4;
    short8 bfrag[8];
#pragma unroll
    for (int kt = 0; kt < 8; ++kt) {
        const bool isOff = (kt < 4);
        const bool valid = isOff ? (n < 8) : (n >= 8);
        const int krow = isOff ? kt : kt - 4;
        const float* wp = isOff ? (off_w + (n < 8 ? n : 0) * CC)
                                : (wt_w + (n >= 8 ? n - 8 : 0) * CC);
        const float* src = wp + chunk * CHUNK + krow * 32 + kg * 8;
        short8 bf;
#pragma unroll
        for (int j = 0; j < 8; ++j) {
            const float v = valid ? src[j] : 0.f;
            bf[j] = (short)f2bf(v);
        }
        bfrag[kt] = bf;
    }

    float w9[9];
#pragma unroll
    for (int j = 0; j < 9; ++j) w9[j] = dw_w[c * 9 + j];
    const float bias = dw_b[c];
    const bool tv = (r0 > 0), bv = (r1 < HH - 1);
    const float wt0 = tv ? w9[0] : 0.f, wt1 = tv ? w9[1] : 0.f, wt2 = tv ? w9[2] : 0.f;
    const float wb0 = bv ? w9[6] : 0.f, wb1 = bv ? w9[7] : 0.f, wb2 = bv ? w9[8] : 0.f;

    const float* base = x + (size_t)b * NN * CC + c;
    const float* rA = base + (size_t)((tv ? r0 - 1 : 0) * WW) * CC;  // r0-1 (clamped)
    const float* rB = base + (size_t)(r0 * WW) * CC;                 // r0
    const float* rC = base + (size_t)(r1 * WW) * CC;                 // r1
    const float* rD = base + (size_t)((bv ? r1 + 1 : r1) * WW) * CC; // r1+1 (clamped)

    float cA[8], cB[8], cC[8], cD[8], nA[8], nB[8], nC[8], nD[8];
    float pA = 0.f, pB = 0.f, pC = 0.f, pD = 0.f;   // column w-1 carries

#pragma unroll
    for (int j = 0; j < 8; ++j) {
        cA[j] = rA[(size_t)j * CC];
        cB[j] = rB[(size_t)j * CC];
        cC[j] = rC[(size_t)j * CC];
        cD[j] = rD[(size_t)j * CC];
    }

    f32x4 accq[4];

#pragma unroll
    for (int q = 0; q < 4; ++q) {
#pragma unroll
        for (int hb = 0; hb < 2; ++hb) {
            const int wbk = q * 2 + hb;
            if (wbk < 7) {
#pragma unroll
                for (int j = 0; j < 8; ++j) {
                    const size_t o = (size_t)(wbk * 8 + 8 + j) * CC;
                    nA[j] = rA[o]; nB[j] = rB[o]; nC[j] = rC[o]; nD[j] = rD[o];
                }
            } else {
#pragma unroll
                for (int j = 0; j < 8; ++j) { nA[j] = 0.f; nB[j] = 0.f; nC[j] = 0.f; nD[j] = 0.f; }
            }
#pragma unroll
            for (int j = 0; j < 8; ++j) {
                const float lA = j ? cA[j - 1] : pA;
                const float lB = j ? cB[j - 1] : pB;
                const float lC = j ? cC[j - 1] : pC;
                const float lD = j ? cD[j - 1] : pD;
                const float rAv = (j == 7) ? nA[0] : cA[j + 1];
                const float rBv = (j == 7) ? nB[0] : cB[j + 1];
                const float rCv = (j == 7) ? nC[0] : cC[j + 1];
                const float rDv = (j == 7) ? nD[0] : cD[j + 1];
                // output row r0: taps rows {A,B,C}; top weights masked at h=0
                const float conv0 = lA * wt0 + cA[j] * wt1 + rAv * wt2
                                  + lB * w9[3] + cB[j] * w9[4] + rBv * w9[5]
                                  + lC * w9[6] + cC[j] * w9[7] + rCv * w9[8];
                // output row r1: taps rows {B,C,D}; bottom weights masked at h=63
                const float conv1 = lB * w9[0] + cB[j] * w9[1] + rBv * w9[2]
                                  + lC * w9[3] + cC[j] * w9[4] + rCv * w9[5]
                                  + lD * wb0 + cD[j] * wb1 + rDv * wb2;
                const int colq = hb * 8 + j;     // column within quarter
                gl[colq][t]      = f2bf(gelu_fast(conv0 + bias));
                gl[16 + colq][t] = f2bf(gelu_fast(conv1 + bias));
                xh[colq][t]      = f2bf(cB[j]);
                xh[16 + colq][t] = f2bf(cC[j]);
            }
            pA = cA[7]; pB = cB[7]; pC = cC[7]; pD = cD[7];
#pragma unroll
            for (int j = 0; j < 8; ++j) { cA[j] = nA[j]; cB[j] = nB[j]; cC[j] = nC[j]; cD[j] = nD[j]; }
        }

        __syncthreads();
        f32x4 acc = {0.f, 0.f, 0.f, 0.f};
        const int arow = wv * 16 + n;
#pragma unroll
        for (int kt = 0; kt < 4; ++kt) {
            const short8 a = *(const short8*)&gl[arow][kt * 32 + kg * 8];
            acc = __builtin_amdgcn_mfma_f32_16x16x32_bf16(a, bfrag[kt], acc, 0, 0, 0);
        }
#pragma unroll
        for (int kt = 0; kt < 4; ++kt) {
            const short8 a = *(const short8*)&xh[arow][kt * 32 + kg * 8];
            acc = __builtin_amdgcn_mfma_f32_16x16x32_bf16(a, bfrag[4 + kt], acc, 0, 0, 0);
        }
        accq[q] = acc;
        if (q < 3) __syncthreads();
    }

    // deferred stores: per plane (chunk*16+n), this block's 64-col row is
    // written in 4 consecutive float4 stores -> full 256 B lines in L2.
    const int r = wv ? r1 : r0;
    const size_t pbase = ((size_t)(chunk * 16 + n)) * (BB * NN)
                       + (size_t)(b * NN) + r * WW + kg * 4;
#pragma unroll
    for (int q = 0; q < 4; ++q) {
        float4 st; st.x = accq[q][0]; st.y = accq[q][1]; st.z = accq[q][2]; st.w = accq[q][3];
        *(float4*)&offpart[pbase + q * 16] = st;
    }
}

// ---------------------------------------------------------------------------
// Combine (coalesced): sum 6 chunk partials, sigmoid gate, shift, clip.
// thread: o = t>>5 (0..7), pos = blk*32 + (t&31)  -> gpos-coalesced reads.
// ---------------------------------------------------------------------------
__global__ __launch_bounds__(256) void dq_combine(
    const float* __restrict__ offpart,  // (NCHUNK, 16, B*N)
    const float* __restrict__ off_b,
    const float* __restrict__ wt_b,
    float* __restrict__ ixiy)           // (2, B*G, N)
{
    const int t = threadIdx.x;
    const int o = t >> 5;
    const int gpos = blockIdx.x * 32 + (t & 31);
    const int b = gpos >> 12;
    const int hw = gpos & 4095;
    const int h = hw >> 6, w = hw & 63;

    float so = 0.f, sw = 0.f;
#pragma unroll
    for (int ch = 0; ch < NCHUNK; ++ch) {
        so += offpart[((size_t)(ch * 16 + o)) * (BB * NN) + gpos];
        sw += offpart[((size_t)(ch * 16 + 8 + o)) * (BB * NN) + gpos];
    }
    const float sig = 1.f / (1.f + __expf(-(sw + wt_b[o])));
    const float val = (so + off_b[o]) * sig;

    if (o < 4) {
        const float shx = (o == 2) ? -1.f : ((o == 3) ? 1.f : 0.f);
        const float ix = fminf(fmaxf((float)w + val + shx, 0.f), (float)(WW - 1));
        ixiy[(b * GG + o) * NN + hw] = ix;
    } else {
        const int g = o - 4;
        const float shy = (g == 0) ? -1.f : ((g == 1) ? 1.f : 0.f);
        const float iy = fminf(fmaxf((float)h + val + shy, 0.f), (float)(HH - 1));
        ixiy[BB * GG * NN + (b * GG + g) * NN + hw] = iy;
    }
}

// ---------------------------------------------------------------------------
// B: bilinear border sampling, float4-vectorized, XCD-swizzled (T1).
// 192 threads, 4 ch/thread; 8 coord loads per block broadcast via LDS.
// ---------------------------------------------------------------------------
__global__ __launch_bounds__(192) void dq_sample_vec(
    const float* __restrict__ x,        // (B, N, C)
    const float* __restrict__ ixiy,     // (2, B*G, N)
    float* __restrict__ out)            // (B, N, C)
{
    __shared__ float ixy[8];            // ix[4], iy[4]
    const int t = threadIdx.x;
    // XCD-aware bijective swizzle: 32768 blocks % 8 XCDs == 0; each XCD walks
    // a contiguous chunk of positions -> bilinear rows stay L2-resident.
    const int p = (blockIdx.x & 7) * (BB * NN / 8) + (blockIdx.x >> 3);
    const int b = p >> 12;
    const int hw = p & 4095;

    if (t < 8) {
        const int g = t & 3;
        const int plane = (t >> 2) * (BB * GG * NN);
        ixy[t] = ixiy[plane + (b * GG + g) * NN + hw];
    }
    __syncthreads();

    const int g = t / 48;               // 48 threads x 4ch = 192 ch per group
    const float ix = ixy[g], iy = ixy[4 + g];
    const float x0f = floorf(ix), y0f = floorf(iy);
    const float wx = ix - x0f, wy = iy - y0f;
    const int x0 = (int)x0f, y0 = (int)y0f;
    const int x1 = min(x0 + 1, WW - 1), y1 = min(y0 + 1, HH - 1);
    const int c4 = t * 4;
    const float* xb = x + (size_t)b * NN * CC;
    const float4 v00 = *(const float4*)(xb + (size_t)(y0 * WW + x0) * CC + c4);
    const float4 v01 = *(const float4*)(xb + (size_t)(y0 * WW + x1) * CC + c4);
    const float4 v10 = *(const float4*)(xb + (size_t)(y1 * WW + x0) * CC + c4);
    const float4 v11 = *(const float4*)(xb + (size_t)(y1 * WW + x1) * CC + c4);
    const float w00 = (1.f - wx) * (1.f - wy), w01 = wx * (1.f - wy);
    const float w10 = (1.f - wx) * wy,         w11 = wx * wy;
    float4 r;
    r.x = v00.x * w00 + v01.x * w01 + v10.x * w10 + v11.x * w11;
    r.y = v00.y * w00 + v01.y * w01 + v10.y * w10 + v11.y * w11;
    r.z = v00.z * w00 + v01.z * w01 + v10.z * w10 + v11.z * w11;
    r.w = v00.w * w00 + v01.w * w01 + v10.w * w10 + v11.w * w11;
    *(float4*)(out + (size_t)p * CC + c4) = r;
}

// ---------------------------------------------------------------------------
// Fallback (small ws): round-1 fused offsets kernel + scalar sampler.
// ---------------------------------------------------------------------------
__global__ __launch_bounds__(256) void dqshift_offsets_kernel(
    const float* __restrict__ x, const float* __restrict__ dw_w,
    const float* __restrict__ dw_b, const float* __restrict__ off_w,
    const float* __restrict__ off_b, const float* __restrict__ wt_w,
    const float* __restrict__ wt_b, float* __restrict__ ixiy)
{
    const int wave = threadIdx.x >> 6;
    const int lane = threadIdx.x & 63;
    const int p = blockIdx.x * 4 + wave;
    const int b = p >> 12;
    const int hw = p & 4095;
    const int h = hw >> 6;
    const int w = hw & 63;
    const float* xb = x + (size_t)b * NN * CC;
    float accO[8], accW[8];
#pragma unroll
    for (int o = 0; o < 8; ++o) { accO[o] = 0.f; accW[o] = 0.f; }
    for (int k = 0; k < CC / 64; ++k) {
        const int c = lane + (k << 6);
        float conv = 0.f, xc = 0.f;
#pragma unroll
        for (int dy = -1; dy <= 1; ++dy) {
            const int hh = h + dy;
            const bool vy = (hh >= 0) && (hh < HH);
#pragma unroll
            for (int dx = -1; dx <= 1; ++dx) {
                const int ww = w + dx;
                const bool vv = vy && (ww >= 0) && (ww < WW);
                const float tt = vv ? xb[(size_t)(hh * WW + ww) * CC + c] : 0.f;
                if (dy == 0 && dx == 0) xc = tt;
                conv = fmaf(tt, dw_w[c * 9 + (dy + 1) * 3 + (dx + 1)], conv);
            }
        }
        const float gv = conv + dw_b[c];
        const float gle = 0.5f * gv * (1.0f + erff(gv * 0.70710678118654752f));
#pragma unroll
        for (int o = 0; o < 8; ++o) {
            accO[o] = fmaf(gle, off_w[o * CC + c], accO[o]);
            accW[o] = fmaf(xc, wt_w[o * CC + c], accW[o]);
        }
    }
#pragma unroll
    for (int o = 0; o < 8; ++o) {
#pragma unroll
        for (int s = 32; s > 0; s >>= 1) {
            accO[o] += __shfl_xor(accO[o], s, 64);
            accW[o] += __shfl_xor(accW[o], s, 64);
        }
    }
    if (lane == 0) {
        const float shx[4] = {0.f, 0.f, -1.f, 1.f};
        const float shy[4] = {-1.f, 1.f, 0.f, 0.f};
#pragma unroll
        for (int g = 0; g < 4; ++g) {
            const float sx = 1.f / (1.f + expf(-(accW[g] + wt_b[g])));
            const float sy = 1.f / (1.f + expf(-(accW[4 + g] + wt_b[4 + g])));
            const float ox = (accO[g] + off_b[g]) * sx + shx[g];
            const float oy = (accO[4 + g] + off_b[4 + g]) * sy + shy[g];
            const float ix = fminf(fmaxf((float)w + ox, 0.f), (float)(WW - 1));
            const float iy = fminf(fmaxf((float)h + oy, 0.f), (float)(HH - 1));
            const int idx = (b * GG + g) * NN + hw;
            ixiy[idx] = ix;
            ixiy[BB * GG * NN + idx] = iy;
        }
    }
}

__global__ __launch_bounds__(256) void dqshift_sample_kernel(
    const float* __restrict__ x,
    const float* __restrict__ ixiy,
    float* __restrict__ out)
{
    const int p = blockIdx.x;
    const int b = p >> 12;
    const int hw = p & 4095;
    const float* xb = x + (size_t)b * NN * CC;
    float* ob = out + (size_t)p * CC;

#pragma unroll
    for (int k = 0; k < 3; ++k) {
        const int c = threadIdx.x + (k << 8);
        const int g = c / (CC / GG);
        const int idx = (b * GG + g) * NN + hw;
        const float ix = ixiy[idx];
        const float iy = ixiy[BB * GG * NN + idx];
        const float x0f = floorf(ix);
        const float y0f = floorf(iy);
        const float wx = ix - x0f;
        const float wy = iy - y0f;
        const int x0 = (int)x0f;
        const int y0 = (int)y0f;
        const int x1 = min(x0 + 1, WW - 1);
        const int y1 = min(y0 + 1, HH - 1);
        const float* r0 = xb + (size_t)(y0 * WW) * CC + c;
        const float* r1 = xb + (size_t)(y1 * WW) * CC + c;
        const float v00 = r0[(size_t)x0 * CC];
        const float v01 = r0[(size_t)x1 * CC];
        const float v10 = r1[(size_t)x0 * CC];
        const float v11 = r1[(size_t)x1 * CC];
        ob[c] = v00 * (1.f - wx) * (1.f - wy) + v01 * wx * (1.f - wy)
              + v10 * (1.f - wx) * wy + v11 * wx * wy;
    }
}

extern "C" void kernel_launch(void* const* d_in, const int* in_sizes, int n_in,
                              void* d_out, int out_size, void* d_ws, size_t ws_size,
                              hipStream_t stream) {
    const float* x     = (const float*)d_in[0];
    const float* dw_w  = (const float*)d_in[1];
    const float* dw_b  = (const float*)d_in[2];
    const float* off_w = (const float*)d_in[3];
    const float* off_b = (const float*)d_in[4];
    const float* wt_w  = (const float*)d_in[5];
    const float* wt_b  = (const float*)d_in[6];

    float* ixiy = (float*)d_ws;                              // 1 MiB
    float* offpart = (float*)d_ws + 2 * BB * GG * NN;        // 12.58 MiB
    const size_t need = (size_t)(2 * BB * GG * NN + NCHUNK * 16 * BB * NN) * 4;

    if (ws_size >= need) {
        dq_conv_mfma<<<BB * (HH / 2) * NCHUNK, 128, 0, stream>>>(
            x, dw_w, dw_b, off_w, wt_w, offpart);
        dq_combine<<<BB * NN / 32, 256, 0, stream>>>(
            offpart, off_b, wt_b, ixiy);
        dq_sample_vec<<<BB * NN, 192, 0, stream>>>(
            x, ixiy, (float*)d_out);
    } else {
        dqshift_offsets_kernel<<<BB * NN / 4, 256, 0, stream>>>(
            x, dw_w, dw_b, off_w, off_b, wt_w, wt_b, ixiy);
        dqshift_sample_kernel<<<BB * NN, 256, 0, stream>>>(x, ixiy, (float*)d_out);
    }
}

// Round 9
// 92.514 us; speedup vs baseline: 1.2783x; 1.0250x over previous
//
#include <hip/hip_runtime.h>
#include <math.h>

// Problem constants: B=8, N=4096, C=768, H=W=64, GROUPS=4.
#define BB 8
#define CC 768
#define HH 64
#define WW 64
#define NN 4096
#define GG 4
#define NCHUNK 6
#define CHUNK 128   /* channels per A1 block */

typedef __attribute__((ext_vector_type(8))) short short8;
typedef __attribute__((ext_vector_type(4))) float f32x4;

__device__ __forceinline__ unsigned short f2bf(float f) {   // RNE float->bf16
    union { float f; unsigned u; } v; v.f = f;
    unsigned r = v.u + 0x7FFFu + ((v.u >> 16) & 1u);
    return (unsigned short)(r >> 16);
}

// tanh-form GELU approx: v * sigmoid(1.5957691*v*(1+0.044715*v^2)).
__device__ __forceinline__ float gelu_fast(float v) {
    const float z = 1.5957691216f * v * fmaf(0.044715f, v * v, 1.0f);
    return __fdividef(v, 1.0f + __expf(-z));
}

// ---------------------------------------------------------------------------
// A1 (1-row blocks for occupancy): block = (b, row h, chunk of 128 ch),
// 128 threads (2 waves), grid 3072 (= 6144 waves = 24/CU demand; LDS 17.4KB
// allows 9 blocks/CU -> ~18 waves/CU ceiling vs round-6's grid-capped 12).
// Row taps {h-1, h, h+1} via clamped pointers + zeroed boundary weights.
// Sliding 3x3 conv along w (batch-8 register prefetch, 24 loads in flight),
// fast GELU; per 32-col half: stage gelu + center-x bf16 in LDS, then
// MFMA D[pos][n] = [gelu|xc] x blockdiag(off_w, wt_w), 8 mfma/wave, store
// immediately (per-half stores proved 18MB HBM writes in r6; deferred
// register accumulators spilled to scratch in r8 -> 60MB. Do NOT defer).
// ---------------------------------------------------------------------------
__global__ __launch_bounds__(128, 4) void dq_conv_mfma(
    const float* __restrict__ x,      // (B, N, C)
    const float* __restrict__ dw_w,   // (C, 9)
    const float* __restrict__ dw_b,   // (C,)
    const float* __restrict__ off_w,  // (8, C)
    const float* __restrict__ wt_w,   // (8, C)
    float* __restrict__ offpart)      // (NCHUNK, 16, B*N)
{
    __shared__ unsigned short gl[32][136];   // gelu bf16: [col-in-half][ch]
    __shared__ unsigned short xh[32][136];   // center x bf16
    const int t = threadIdx.x;
    const int lane = t & 63, wv = t >> 6;
    int bid = blockIdx.x;
    const int chunk = bid % NCHUNK; bid /= NCHUNK;
    const int h = bid % HH;
    const int b = bid / HH;
    const int c = chunk * CHUNK + t;

    // ---- B fragments: blockdiag [off_w ; wt_w], built once ----
    const int n = lane & 15, kg = lane >> 4;
    short8 bfrag[8];
#pragma unroll
    for (int kt = 0; kt < 8; ++kt) {
        const bool isOff = (kt < 4);
        const bool valid = isOff ? (n < 8) : (n >= 8);
        const int krow = isOff ? kt : kt - 4;
        const float* wp = isOff ? (off_w + (n < 8 ? n : 0) * CC)
                                : (wt_w + (n >= 8 ? n - 8 : 0) * CC);
        const float* src = wp + chunk * CHUNK + krow * 32 + kg * 8;
        short8 bf;
#pragma unroll
        for (int j = 0; j < 8; ++j) {
            const float v = valid ? src[j] : 0.f;
            bf[j] = (short)f2bf(v);
        }
        bfrag[kt] = bf;
    }

    float w9[9];
#pragma unroll
    for (int j = 0; j < 9; ++j) w9[j] = dw_w[c * 9 + j];
    const float bias = dw_b[c];
    const bool tv = (h > 0), bv = (h < HH - 1);
    // boundary rows: clamp pointer, zero the tap weights (no per-load selects)
    const float wt0 = tv ? w9[0] : 0.f, wt1 = tv ? w9[1] : 0.f, wt2 = tv ? w9[2] : 0.f;
    const float wb0 = bv ? w9[6] : 0.f, wb1 = bv ? w9[7] : 0.f, wb2 = bv ? w9[8] : 0.f;

    const float* base = x + (size_t)b * NN * CC + c;
    const float* rT = base + (size_t)((tv ? h - 1 : 0) * WW) * CC;   // h-1 (clamped)
    const float* rM = base + (size_t)(h * WW) * CC;                  // h
    const float* rB = base + (size_t)((bv ? h + 1 : h) * WW) * CC;   // h+1 (clamped)

    float cT[8], cM[8], cB[8], nT[8], nM[8], nB[8];
    float pT = 0.f, pM = 0.f, pB = 0.f;   // column w-1 carries

#pragma unroll
    for (int j = 0; j < 8; ++j) {
        const size_t o = (size_t)j * CC;
        cT[j] = rT[o]; cM[j] = rM[o]; cB[j] = rB[o];
    }

    for (int wb = 0; wb < 8; ++wb) {
        if (wb < 7) {
#pragma unroll
            for (int j = 0; j < 8; ++j) {
                const size_t o = (size_t)(wb * 8 + 8 + j) * CC;
                nT[j] = rT[o]; nM[j] = rM[o]; nB[j] = rB[o];
            }
        } else {
#pragma unroll
            for (int j = 0; j < 8; ++j) { nT[j] = 0.f; nM[j] = 0.f; nB[j] = 0.f; }
        }
#pragma unroll
        for (int j = 0; j < 8; ++j) {
            const float lT = j ? cT[j - 1] : pT;
            const float lM = j ? cM[j - 1] : pM;
            const float lB = j ? cB[j - 1] : pB;
            const float rTv = (j == 7) ? nT[0] : cT[j + 1];
            const float rMv = (j == 7) ? nM[0] : cM[j + 1];
            const float rBv = (j == 7) ? nB[0] : cB[j + 1];
            const float conv = lT * wt0 + cT[j] * wt1 + rTv * wt2
                             + lM * w9[3] + cM[j] * w9[4] + rMv * w9[5]
                             + lB * wb0 + cB[j] * wb1 + rBv * wb2;
            const int colh = (wb & 3) * 8 + j;     // column within half
            gl[colh][t] = f2bf(gelu_fast(conv + bias));
            xh[colh][t] = f2bf(cM[j]);
        }
        pT = cT[7]; pM = cM[7]; pB = cB[7];
#pragma unroll
        for (int j = 0; j < 8; ++j) { cT[j] = nT[j]; cM[j] = nM[j]; cB[j] = nB[j]; }

        if ((wb & 3) == 3) {                 // end of 32-col half
            const int half = wb >> 2;
            __syncthreads();
            // wave wv covers cols half*32 + wv*16 .. +15
            f32x4 acc = {0.f, 0.f, 0.f, 0.f};
            const int arow = wv * 16 + n;
#pragma unroll
            for (int kt = 0; kt < 4; ++kt) {
                const short8 a = *(const short8*)&gl[arow][kt * 32 + kg * 8];
                acc = __builtin_amdgcn_mfma_f32_16x16x32_bf16(a, bfrag[kt], acc, 0, 0, 0);
            }
#pragma unroll
            for (int kt = 0; kt < 4; ++kt) {
                const short8 a = *(const short8*)&xh[arow][kt * 32 + kg * 8];
                acc = __builtin_amdgcn_mfma_f32_16x16x32_bf16(a, bfrag[4 + kt], acc, 0, 0, 0);
            }
            // D: col n = plane, rows kg*4..+3 = 4 consecutive positions
            const size_t gpos = (size_t)(b * NN) + h * WW + half * 32 + wv * 16 + kg * 4;
            float4 st; st.x = acc[0]; st.y = acc[1]; st.z = acc[2]; st.w = acc[3];
            *(float4*)&offpart[((size_t)(chunk * 16 + n)) * (BB * NN) + gpos] = st;
            if (wb < 7) __syncthreads();
        }
    }
}

// ---------------------------------------------------------------------------
// Combine (coalesced): sum 6 chunk partials, sigmoid gate, shift, clip.
// thread: o = t>>5 (0..7), pos = blk*32 + (t&31)  -> gpos-coalesced reads.
// ---------------------------------------------------------------------------
__global__ __launch_bounds__(256) void dq_combine(
    const float* __restrict__ offpart,  // (NCHUNK, 16, B*N)
    const float* __restrict__ off_b,
    const float* __restrict__ wt_b,
    float* __restrict__ ixiy)           // (2, B*G, N)
{
    const int t = threadIdx.x;
    const int o = t >> 5;
    const int gpos = blockIdx.x * 32 + (t & 31);
    const int b = gpos >> 12;
    const int hw = gpos & 4095;
    const int h = hw >> 6, w = hw & 63;

    float so = 0.f, sw = 0.f;
#pragma unroll
    for (int ch = 0; ch < NCHUNK; ++ch) {
        so += offpart[((size_t)(ch * 16 + o)) * (BB * NN) + gpos];
        sw += offpart[((size_t)(ch * 16 + 8 + o)) * (BB * NN) + gpos];
    }
    const float sig = 1.f / (1.f + __expf(-(sw + wt_b[o])));
    const float val = (so + off_b[o]) * sig;

    if (o < 4) {
        const float shx = (o == 2) ? -1.f : ((o == 3) ? 1.f : 0.f);
        const float ix = fminf(fmaxf((float)w + val + shx, 0.f), (float)(WW - 1));
        ixiy[(b * GG + o) * NN + hw] = ix;
    } else {
        const int g = o - 4;
        const float shy = (g == 0) ? -1.f : ((g == 1) ? 1.f : 0.f);
        const float iy = fminf(fmaxf((float)h + val + shy, 0.f), (float)(HH - 1));
        ixiy[BB * GG * NN + (b * GG + g) * NN + hw] = iy;
    }
}

// ---------------------------------------------------------------------------
// B: bilinear border sampling, float4-vectorized, XCD-swizzled (T1).
// 192 threads, 4 ch/thread; 8 coord loads per block broadcast via LDS.
// ---------------------------------------------------------------------------
__global__ __launch_bounds__(192) void dq_sample_vec(
    const float* __restrict__ x,        // (B, N, C)
    const float* __restrict__ ixiy,     // (2, B*G, N)
    float* __restrict__ out)            // (B, N, C)
{
    __shared__ float ixy[8];            // ix[4], iy[4]
    const int t = threadIdx.x;
    // XCD-aware bijective swizzle: 32768 blocks % 8 XCDs == 0; each XCD walks
    // a contiguous chunk of positions -> bilinear rows stay L2-resident.
    const int p = (blockIdx.x & 7) * (BB * NN / 8) + (blockIdx.x >> 3);
    const int b = p >> 12;
    const int hw = p & 4095;

    if (t < 8) {
        const int g = t & 3;
        const int plane = (t >> 2) * (BB * GG * NN);
        ixy[t] = ixiy[plane + (b * GG + g) * NN + hw];
    }
    __syncthreads();

    const int g = t / 48;               // 48 threads x 4ch = 192 ch per group
    const float ix = ixy[g], iy = ixy[4 + g];
    const float x0f = floorf(ix), y0f = floorf(iy);
    const float wx = ix - x0f, wy = iy - y0f;
    const int x0 = (int)x0f, y0 = (int)y0f;
    const int x1 = min(x0 + 1, WW - 1), y1 = min(y0 + 1, HH - 1);
    const int c4 = t * 4;
    const float* xb = x + (size_t)b * NN * CC;
    const float4 v00 = *(const float4*)(xb + (size_t)(y0 * WW + x0) * CC + c4);
    const float4 v01 = *(const float4*)(xb + (size_t)(y0 * WW + x1) * CC + c4);
    const float4 v10 = *(const float4*)(xb + (size_t)(y1 * WW + x0) * CC + c4);
    const float4 v11 = *(const float4*)(xb + (size_t)(y1 * WW + x1) * CC + c4);
    const float w00 = (1.f - wx) * (1.f - wy), w01 = wx * (1.f - wy);
    const float w10 = (1.f - wx) * wy,         w11 = wx * wy;
    float4 r;
    r.x = v00.x * w00 + v01.x * w01 + v10.x * w10 + v11.x * w11;
    r.y = v00.y * w00 + v01.y * w01 + v10.y * w10 + v11.y * w11;
    r.z = v00.z * w00 + v01.z * w01 + v10.z * w10 + v11.z * w11;
    r.w = v00.w * w00 + v01.w * w01 + v10.w * w10 + v11.w * w11;
    *(float4*)(out + (size_t)p * CC + c4) = r;
}

// ---------------------------------------------------------------------------
// Fallback (small ws): round-1 fused offsets kernel + scalar sampler.
// ---------------------------------------------------------------------------
__global__ __launch_bounds__(256) void dqshift_offsets_kernel(
    const float* __restrict__ x, const float* __restrict__ dw_w,
    const float* __restrict__ dw_b, const float* __restrict__ off_w,
    const float* __restrict__ off_b, const float* __restrict__ wt_w,
    const float* __restrict__ wt_b, float* __restrict__ ixiy)
{
    const int wave = threadIdx.x >> 6;
    const int lane = threadIdx.x & 63;
    const int p = blockIdx.x * 4 + wave;
    const int b = p >> 12;
    const int hw = p & 4095;
    const int h = hw >> 6;
    const int w = hw & 63;
    const float* xb = x + (size_t)b * NN * CC;
    float accO[8], accW[8];
#pragma unroll
    for (int o = 0; o < 8; ++o) { accO[o] = 0.f; accW[o] = 0.f; }
    for (int k = 0; k < CC / 64; ++k) {
        const int c = lane + (k << 6);
        float conv = 0.f, xc = 0.f;
#pragma unroll
        for (int dy = -1; dy <= 1; ++dy) {
            const int hh = h + dy;
            const bool vy = (hh >= 0) && (hh < HH);
#pragma unroll
            for (int dx = -1; dx <= 1; ++dx) {
                const int ww = w + dx;
                const bool vv = vy && (ww >= 0) && (ww < WW);
                const float tt = vv ? xb[(size_t)(hh * WW + ww) * CC + c] : 0.f;
                if (dy == 0 && dx == 0) xc = tt;
                conv = fmaf(tt, dw_w[c * 9 + (dy + 1) * 3 + (dx + 1)], conv);
            }
        }
        const float gv = conv + dw_b[c];
        const float gle = 0.5f * gv * (1.0f + erff(gv * 0.70710678118654752f));
#pragma unroll
        for (int o = 0; o < 8; ++o) {
            accO[o] = fmaf(gle, off_w[o * CC + c], accO[o]);
            accW[o] = fmaf(xc, wt_w[o * CC + c], accW[o]);
        }
    }
#pragma unroll
    for (int o = 0; o < 8; ++o) {
#pragma unroll
        for (int s = 32; s > 0; s >>= 1) {
            accO[o] += __shfl_xor(accO[o], s, 64);
            accW[o] += __shfl_xor(accW[o], s, 64);
        }
    }
    if (lane == 0) {
        const float shx[4] = {0.f, 0.f, -1.f, 1.f};
        const float shy[4] = {-1.f, 1.f, 0.f, 0.f};
#pragma unroll
        for (int g = 0; g < 4; ++g) {
            const float sx = 1.f / (1.f + expf(-(accW[g] + wt_b[g])));
            const float sy = 1.f / (1.f + expf(-(accW[4 + g] + wt_b[4 + g])));
            const float ox = (accO[g] + off_b[g]) * sx + shx[g];
            const float oy = (accO[4 + g] + off_b[4 + g]) * sy + shy[g];
            const float ix = fminf(fmaxf((float)w + ox, 0.f), (float)(WW - 1));
            const float iy = fminf(fmaxf((float)h + oy, 0.f), (float)(HH - 1));
            const int idx = (b * GG + g) * NN + hw;
            ixiy[idx] = ix;
            ixiy[BB * GG * NN + idx] = iy;
        }
    }
}

__global__ __launch_bounds__(256) void dqshift_sample_kernel(
    const float* __restrict__ x,
    const float* __restrict__ ixiy,
    float* __restrict__ out)
{
    const int p = blockIdx.x;
    const int b = p >> 12;
    const int hw = p & 4095;
    const float* xb = x + (size_t)b * NN * CC;
    float* ob = out + (size_t)p * CC;

#pragma unroll
    for (int k = 0; k < 3; ++k) {
        const int c = threadIdx.x + (k << 8);
        const int g = c / (CC / GG);
        const int idx = (b * GG + g) * NN + hw;
        const float ix = ixiy[idx];
        const float iy = ixiy[BB * GG * NN + idx];
        const float x0f = floorf(ix);
        const float y0f = floorf(iy);
        const float wx = ix - x0f;
        const float wy = iy - y0f;
        const int x0 = (int)x0f;
        const int y0 = (int)y0f;
        const int x1 = min(x0 + 1, WW - 1);
        const int y1 = min(y0 + 1, HH - 1);
        const float* r0 = xb + (size_t)(y0 * WW) * CC + c;
        const float* r1 = xb + (size_t)(y1 * WW) * CC + c;
        const float v00 = r0[(size_t)x0 * CC];
        const float v01 = r0[(size_t)x1 * CC];
        const float v10 = r1[(size_t)x0 * CC];
        const float v11 = r1[(size_t)x1 * CC];
        ob[c] = v00 * (1.f - wx) * (1.f - wy) + v01 * wx * (1.f - wy)
              + v10 * (1.f - wx) * wy + v11 * wx * wy;
    }
}

extern "C" void kernel_launch(void* const* d_in, const int* in_sizes, int n_in,
                              void* d_out, int out_size, void* d_ws, size_t ws_size,
                              hipStream_t stream) {
    const float* x     = (const float*)d_in[0];
    const float* dw_w  = (const float*)d_in[1];
    const float* dw_b  = (const float*)d_in[2];
    const float* off_w = (const float*)d_in[3];
    const float* off_b = (const float*)d_in[4];
    const float* wt_w  = (const float*)d_in[5];
    const float* wt_b  = (const float*)d_in[6];

    float* ixiy = (float*)d_ws;                              // 1 MiB
    float* offpart = (float*)d_ws + 2 * BB * GG * NN;        // 12.58 MiB
    const size_t need = (size_t)(2 * BB * GG * NN + NCHUNK * 16 * BB * NN) * 4;

    if (ws_size >= need) {
        dq_conv_mfma<<<BB * HH * NCHUNK, 128, 0, stream>>>(
            x, dw_w, dw_b, off_w, wt_w, offpart);
        dq_combine<<<BB * NN / 32, 256, 0, stream>>>(
            offpart, off_b, wt_b, ixiy);
        dq_sample_vec<<<BB * NN, 192, 0, stream>>>(
            x, ixiy, (float*)d_out);
    } else {
        dqshift_offsets_kernel<<<BB * NN / 4, 256, 0, stream>>>(
            x, dw_w, dw_b, off_w, off_b, wt_w, wt_b, ixiy);
        dqshift_sample_kernel<<<BB * NN, 256, 0, stream>>>(x, ixiy, (float*)d_out);
    }
}

// Round 10
// 87.471 us; speedup vs baseline: 1.3520x; 1.0576x over previous
//
#include <hip/hip_runtime.h>
#include <math.h>

// Problem constants: B=8, N=4096, C=768, H=W=64, GROUPS=4.
#define BB 8
#define CC 768
#define HH 64
#define WW 64
#define NN 4096
#define GG 4
#define NCHUNK 6
#define CHUNK 128   /* channels per A1 block */

typedef __attribute__((ext_vector_type(8))) short short8;
typedef __attribute__((ext_vector_type(4))) float f32x4;

__device__ __forceinline__ unsigned short f2bf(float f) {   // RNE float->bf16
    union { float f; unsigned u; } v; v.f = f;
    unsigned r = v.u + 0x7FFFu + ((v.u >> 16) & 1u);
    return (unsigned short)(r >> 16);
}

// tanh-form GELU approx: v * sigmoid(1.5957691*v*(1+0.044715*v^2)).
__device__ __forceinline__ float gelu_fast(float v) {
    const float z = 1.5957691216f * v * fmaf(0.044715f, v * v, 1.0f);
    return __fdividef(v, 1.0f + __expf(-z));
}

// ---------------------------------------------------------------------------
// A1 (wave-specialized, 9KB LDS): block = (b, row h, chunk of 128 ch),
// 128 threads (2 waves), grid 3072.
// r5/r6/r9 all plateaued at ~63us with 17.4KB LDS and ~33% occupancy
// (resident-block limited). Halve LDS by staging only a 16-col quarter:
// gl[16][144] + xh[16][144] = 9KB -> LDS cap 17 blocks/CU, grid cap 12.
// MFMA wave-specialization (no blockdiag zero-waste): wave0 computes
// gelu x off_w (planes n<8), wave1 computes x x wt_w (planes 8+n).
// Each wave: 4 MFMA + 4 ds_read_b128 per quarter. Stride 144 ush = 288B
// keeps b128 reads 16B-aligned at ~4-way banks (136 was 8-way).
// Stores stay immediate/per-quarter (r8 proved deferring spills to scratch).
// ---------------------------------------------------------------------------
__global__ __launch_bounds__(128, 4) void dq_conv_mfma(
    const float* __restrict__ x,      // (B, N, C)
    const float* __restrict__ dw_w,   // (C, 9)
    const float* __restrict__ dw_b,   // (C,)
    const float* __restrict__ off_w,  // (8, C)
    const float* __restrict__ wt_w,   // (8, C)
    float* __restrict__ offpart)      // (NCHUNK, 16, B*N)
{
    __shared__ unsigned short gl[16][144];   // gelu bf16: [col-in-quarter][ch]
    __shared__ unsigned short xh[16][144];   // center x bf16
    const int t = threadIdx.x;
    const int lane = t & 63, wv = t >> 6;
    int bid = blockIdx.x;
    const int chunk = bid % NCHUNK; bid /= NCHUNK;
    const int h = bid % HH;
    const int b = bid / HH;
    const int c = chunk * CHUNK + t;

    // ---- B fragments: wave0 = off_w, wave1 = wt_w (rows n<8 valid) ----
    const int n = lane & 15, kg = lane >> 4;
    const float* wsrc = (wv == 0) ? off_w : wt_w;
    short8 bfrag[4];
#pragma unroll
    for (int kt = 0; kt < 4; ++kt) {
        const bool valid = (n < 8);
        const float* src = wsrc + (valid ? n : 0) * CC + chunk * CHUNK + kt * 32 + kg * 8;
        short8 bf;
#pragma unroll
        for (int j = 0; j < 8; ++j) {
            const float v = valid ? src[j] : 0.f;
            bf[j] = (short)f2bf(v);
        }
        bfrag[kt] = bf;
    }

    float w9[9];
#pragma unroll
    for (int j = 0; j < 9; ++j) w9[j] = dw_w[c * 9 + j];
    const float bias = dw_b[c];
    const bool tv = (h > 0), bv = (h < HH - 1);
    // boundary rows: clamp pointer, zero the tap weights (no per-load selects)
    const float wt0 = tv ? w9[0] : 0.f, wt1 = tv ? w9[1] : 0.f, wt2 = tv ? w9[2] : 0.f;
    const float wb0 = bv ? w9[6] : 0.f, wb1 = bv ? w9[7] : 0.f, wb2 = bv ? w9[8] : 0.f;

    const float* base = x + (size_t)b * NN * CC + c;
    const float* rT = base + (size_t)((tv ? h - 1 : 0) * WW) * CC;   // h-1 (clamped)
    const float* rM = base + (size_t)(h * WW) * CC;                  // h
    const float* rB = base + (size_t)((bv ? h + 1 : h) * WW) * CC;   // h+1 (clamped)

    float cT[8], cM[8], cB[8], nT[8], nM[8], nB[8];
    float pT = 0.f, pM = 0.f, pB = 0.f;   // column w-1 carries

#pragma unroll
    for (int j = 0; j < 8; ++j) {
        const size_t o = (size_t)j * CC;
        cT[j] = rT[o]; cM[j] = rM[o]; cB[j] = rB[o];
    }

#pragma unroll
    for (int q = 0; q < 4; ++q) {
#pragma unroll
        for (int hb = 0; hb < 2; ++hb) {
            const int wb = q * 2 + hb;
            if (wb < 7) {
#pragma unroll
                for (int j = 0; j < 8; ++j) {
                    const size_t o = (size_t)(wb * 8 + 8 + j) * CC;
                    nT[j] = rT[o]; nM[j] = rM[o]; nB[j] = rB[o];
                }
            } else {
#pragma unroll
                for (int j = 0; j < 8; ++j) { nT[j] = 0.f; nM[j] = 0.f; nB[j] = 0.f; }
            }
#pragma unroll
            for (int j = 0; j < 8; ++j) {
                const float lT = j ? cT[j - 1] : pT;
                const float lM = j ? cM[j - 1] : pM;
                const float lB = j ? cB[j - 1] : pB;
                const float rTv = (j == 7) ? nT[0] : cT[j + 1];
                const float rMv = (j == 7) ? nM[0] : cM[j + 1];
                const float rBv = (j == 7) ? nB[0] : cB[j + 1];
                const float conv = lT * wt0 + cT[j] * wt1 + rTv * wt2
                                 + lM * w9[3] + cM[j] * w9[4] + rMv * w9[5]
                                 + lB * wb0 + cB[j] * wb1 + rBv * wb2;
                const int colq = hb * 8 + j;     // column within quarter
                gl[colq][t] = f2bf(gelu_fast(conv + bias));
                xh[colq][t] = f2bf(cM[j]);
            }
            pT = cT[7]; pM = cM[7]; pB = cB[7];
#pragma unroll
            for (int j = 0; j < 8; ++j) { cT[j] = nT[j]; cM[j] = nM[j]; cB[j] = nB[j]; }
        }

        __syncthreads();
        // wave 0: gelu x off_w; wave 1: center-x x wt_w. A-row = n (col in quarter).
        f32x4 acc = {0.f, 0.f, 0.f, 0.f};
        if (wv == 0) {
#pragma unroll
            for (int kt = 0; kt < 4; ++kt) {
                const short8 a = *(const short8*)&gl[n][kt * 32 + kg * 8];
                acc = __builtin_amdgcn_mfma_f32_16x16x32_bf16(a, bfrag[kt], acc, 0, 0, 0);
            }
        } else {
#pragma unroll
            for (int kt = 0; kt < 4; ++kt) {
                const short8 a = *(const short8*)&xh[n][kt * 32 + kg * 8];
                acc = __builtin_amdgcn_mfma_f32_16x16x32_bf16(a, bfrag[kt], acc, 0, 0, 0);
            }
        }
        // D: col n = plane (n<8 valid), rows kg*4..+3 = 4 consecutive positions
        if (n < 8) {
            const int plane = chunk * 16 + (wv ? 8 + n : n);
            const size_t gpos = (size_t)(b * NN) + h * WW + q * 16 + kg * 4;
            float4 st; st.x = acc[0]; st.y = acc[1]; st.z = acc[2]; st.w = acc[3];
            *(float4*)&offpart[(size_t)plane * (BB * NN) + gpos] = st;
        }
        if (q < 3) __syncthreads();
    }
}

// ---------------------------------------------------------------------------
// Combine (coalesced): sum 6 chunk partials, sigmoid gate, shift, clip.
// thread: o = t>>5 (0..7), pos = blk*32 + (t&31)  -> gpos-coalesced reads.
// ---------------------------------------------------------------------------
__global__ __launch_bounds__(256) void dq_combine(
    const float* __restrict__ offpart,  // (NCHUNK, 16, B*N)
    const float* __restrict__ off_b,
    const float* __restrict__ wt_b,
    float* __restrict__ ixiy)           // (2, B*G, N)
{
    const int t = threadIdx.x;
    const int o = t >> 5;
    const int gpos = blockIdx.x * 32 + (t & 31);
    const int b = gpos >> 12;
    const int hw = gpos & 4095;
    const int h = hw >> 6, w = hw & 63;

    float so = 0.f, sw = 0.f;
#pragma unroll
    for (int ch = 0; ch < NCHUNK; ++ch) {
        so += offpart[((size_t)(ch * 16 + o)) * (BB * NN) + gpos];
        sw += offpart[((size_t)(ch * 16 + 8 + o)) * (BB * NN) + gpos];
    }
    const float sig = 1.f / (1.f + __expf(-(sw + wt_b[o])));
    const float val = (so + off_b[o]) * sig;

    if (o < 4) {
        const float shx = (o == 2) ? -1.f : ((o == 3) ? 1.f : 0.f);
        const float ix = fminf(fmaxf((float)w + val + shx, 0.f), (float)(WW - 1));
        ixiy[(b * GG + o) * NN + hw] = ix;
    } else {
        const int g = o - 4;
        const float shy = (g == 0) ? -1.f : ((g == 1) ? 1.f : 0.f);
        const float iy = fminf(fmaxf((float)h + val + shy, 0.f), (float)(HH - 1));
        ixiy[BB * GG * NN + (b * GG + g) * NN + hw] = iy;
    }
}

// ---------------------------------------------------------------------------
// B: bilinear border sampling, float4-vectorized, XCD-swizzled (T1).
// 192 threads, 4 ch/thread; 8 coord loads per block broadcast via LDS.
// ---------------------------------------------------------------------------
__global__ __launch_bounds__(192) void dq_sample_vec(
    const float* __restrict__ x,        // (B, N, C)
    const float* __restrict__ ixiy,     // (2, B*G, N)
    float* __restrict__ out)            // (B, N, C)
{
    __shared__ float ixy[8];            // ix[4], iy[4]
    const int t = threadIdx.x;
    // XCD-aware bijective swizzle: 32768 blocks % 8 XCDs == 0; each XCD walks
    // a contiguous chunk of positions -> bilinear rows stay L2-resident.
    const int p = (blockIdx.x & 7) * (BB * NN / 8) + (blockIdx.x >> 3);
    const int b = p >> 12;
    const int hw = p & 4095;

    if (t < 8) {
        const int g = t & 3;
        const int plane = (t >> 2) * (BB * GG * NN);
        ixy[t] = ixiy[plane + (b * GG + g) * NN + hw];
    }
    __syncthreads();

    const int g = t / 48;               // 48 threads x 4ch = 192 ch per group
    const float ix = ixy[g], iy = ixy[4 + g];
    const float x0f = floorf(ix), y0f = floorf(iy);
    const float wx = ix - x0f, wy = iy - y0f;
    const int x0 = (int)x0f, y0 = (int)y0f;
    const int x1 = min(x0 + 1, WW - 1), y1 = min(y0 + 1, HH - 1);
    const int c4 = t * 4;
    const float* xb = x + (size_t)b * NN * CC;
    const float4 v00 = *(const float4*)(xb + (size_t)(y0 * WW + x0) * CC + c4);
    const float4 v01 = *(const float4*)(xb + (size_t)(y0 * WW + x1) * CC + c4);
    const float4 v10 = *(const float4*)(xb + (size_t)(y1 * WW + x0) * CC + c4);
    const float4 v11 = *(const float4*)(xb + (size_t)(y1 * WW + x1) * CC + c4);
    const float w00 = (1.f - wx) * (1.f - wy), w01 = wx * (1.f - wy);
    const float w10 = (1.f - wx) * wy,         w11 = wx * wy;
    float4 r;
    r.x = v00.x * w00 + v01.x * w01 + v10.x * w10 + v11.x * w11;
    r.y = v00.y * w00 + v01.y * w01 + v10.y * w10 + v11.y * w11;
    r.z = v00.z * w00 + v01.z * w01 + v10.z * w10 + v11.z * w11;
    r.w = v00.w * w00 + v01.w * w01 + v10.w * w10 + v11.w * w11;
    *(float4*)(out + (size_t)p * CC + c4) = r;
}

// ---------------------------------------------------------------------------
// Fallback (small ws): round-1 fused offsets kernel + scalar sampler.
// ---------------------------------------------------------------------------
__global__ __launch_bounds__(256) void dqshift_offsets_kernel(
    const float* __restrict__ x, const float* __restrict__ dw_w,
    const float* __restrict__ dw_b, const float* __restrict__ off_w,
    const float* __restrict__ off_b, const float* __restrict__ wt_w,
    const float* __restrict__ wt_b, float* __restrict__ ixiy)
{
    const int wave = threadIdx.x >> 6;
    const int lane = threadIdx.x & 63;
    const int p = blockIdx.x * 4 + wave;
    const int b = p >> 12;
    const int hw = p & 4095;
    const int h = hw >> 6;
    const int w = hw & 63;
    const float* xb = x + (size_t)b * NN * CC;
    float accO[8], accW[8];
#pragma unroll
    for (int o = 0; o < 8; ++o) { accO[o] = 0.f; accW[o] = 0.f; }
    for (int k = 0; k < CC / 64; ++k) {
        const int c = lane + (k << 6);
        float conv = 0.f, xc = 0.f;
#pragma unroll
        for (int dy = -1; dy <= 1; ++dy) {
            const int hh = h + dy;
            const bool vy = (hh >= 0) && (hh < HH);
#pragma unroll
            for (int dx = -1; dx <= 1; ++dx) {
                const int ww = w + dx;
                const bool vv = vy && (ww >= 0) && (ww < WW);
                const float tt = vv ? xb[(size_t)(hh * WW + ww) * CC + c] : 0.f;
                if (dy == 0 && dx == 0) xc = tt;
                conv = fmaf(tt, dw_w[c * 9 + (dy + 1) * 3 + (dx + 1)], conv);
            }
        }
        const float gv = conv + dw_b[c];
        const float gle = 0.5f * gv * (1.0f + erff(gv * 0.70710678118654752f));
#pragma unroll
        for (int o = 0; o < 8; ++o) {
            accO[o] = fmaf(gle, off_w[o * CC + c], accO[o]);
            accW[o] = fmaf(xc, wt_w[o * CC + c], accW[o]);
        }
    }
#pragma unroll
    for (int o = 0; o < 8; ++o) {
#pragma unroll
        for (int s = 32; s > 0; s >>= 1) {
            accO[o] += __shfl_xor(accO[o], s, 64);
            accW[o] += __shfl_xor(accW[o], s, 64);
        }
    }
    if (lane == 0) {
        const float shx[4] = {0.f, 0.f, -1.f, 1.f};
        const float shy[4] = {-1.f, 1.f, 0.f, 0.f};
#pragma unroll
        for (int g = 0; g < 4; ++g) {
            const float sx = 1.f / (1.f + expf(-(accW[g] + wt_b[g])));
            const float sy = 1.f / (1.f + expf(-(accW[4 + g] + wt_b[4 + g])));
            const float ox = (accO[g] + off_b[g]) * sx + shx[g];
            const float oy = (accO[4 + g] + off_b[4 + g]) * sy + shy[g];
            const float ix = fminf(fmaxf((float)w + ox, 0.f), (float)(WW - 1));
            const float iy = fminf(fmaxf((float)h + oy, 0.f), (float)(HH - 1));
            const int idx = (b * GG + g) * NN + hw;
            ixiy[idx] = ix;
            ixiy[BB * GG * NN + idx] = iy;
        }
    }
}

__global__ __launch_bounds__(256) void dqshift_sample_kernel(
    const float* __restrict__ x,
    const float* __restrict__ ixiy,
    float* __restrict__ out)
{
    const int p = blockIdx.x;
    const int b = p >> 12;
    const int hw = p & 4095;
    const float* xb = x + (size_t)b * NN * CC;
    float* ob = out + (size_t)p * CC;

#pragma unroll
    for (int k = 0; k < 3; ++k) {
        const int c = threadIdx.x + (k << 8);
        const int g = c / (CC / GG);
        const int idx = (b * GG + g) * NN + hw;
        const float ix = ixiy[idx];
        const float iy = ixiy[BB * GG * NN + idx];
        const float x0f = floorf(ix);
        const float y0f = floorf(iy);
        const float wx = ix - x0f;
        const float wy = iy - y0f;
        const int x0 = (int)x0f;
        const int y0 = (int)y0f;
        const int x1 = min(x0 + 1, WW - 1);
        const int y1 = min(y0 + 1, HH - 1);
        const float* r0 = xb + (size_t)(y0 * WW) * CC + c;
        const float* r1 = xb + (size_t)(y1 * WW) * CC + c;
        const float v00 = r0[(size_t)x0 * CC];
        const float v01 = r0[(size_t)x1 * CC];
        const float v10 = r1[(size_t)x0 * CC];
        const float v11 = r1[(size_t)x1 * CC];
        ob[c] = v00 * (1.f - wx) * (1.f - wy) + v01 * wx * (1.f - wy)
              + v10 * (1.f - wx) * wy + v11 * wx * wy;
    }
}

extern "C" void kernel_launch(void* const* d_in, const int* in_sizes, int n_in,
                              void* d_out, int out_size, void* d_ws, size_t ws_size,
                              hipStream_t stream) {
    const float* x     = (const float*)d_in[0];
    const float* dw_w  = (const float*)d_in[1];
    const float* dw_b  = (const float*)d_in[2];
    const float* off_w = (const float*)d_in[3];
    const float* off_b = (const float*)d_in[4];
    const float* wt_w  = (const float*)d_in[5];
    const float* wt_b  = (const float*)d_in[6];

    float* ixiy = (float*)d_ws;                              // 1 MiB
    float* offpart = (float*)d_ws + 2 * BB * GG * NN;        // 12.58 MiB
    const size_t need = (size_t)(2 * BB * GG * NN + NCHUNK * 16 * BB * NN) * 4;

    if (ws_size >= need) {
        dq_conv_mfma<<<BB * HH * NCHUNK, 128, 0, stream>>>(
            x, dw_w, dw_b, off_w, wt_w, offpart);
        dq_combine<<<BB * NN / 32, 256, 0, stream>>>(
            offpart, off_b, wt_b, ixiy);
        dq_sample_vec<<<BB * NN, 192, 0, stream>>>(
            x, ixiy, (float*)d_out);
    } else {
        dqshift_offsets_kernel<<<BB * NN / 4, 256, 0, stream>>>(
            x, dw_w, dw_b, off_w, off_b, wt_w, wt_b, ixiy);
        dqshift_sample_kernel<<<BB * NN, 256, 0, stream>>>(x, ixiy, (float*)d_out);
    }
}

// Round 11
// 76.182 us; speedup vs baseline: 1.5524x; 1.1482x over previous
//
#include <hip/hip_runtime.h>
#include <math.h>

// Problem constants: B=8, N=4096, C=768, H=W=64, GROUPS=4.
#define BB 8
#define CC 768
#define HH 64
#define WW 64
#define NN 4096
#define GG 4
#define NCHUNK 6
#define CHUNK 128   /* channels per A1 block */

typedef __attribute__((ext_vector_type(8))) short short8;
typedef __attribute__((ext_vector_type(4))) float f32x4;

__device__ __forceinline__ unsigned short f2bf(float f) {   // RNE float->bf16
    union { float f; unsigned u; } v; v.f = f;
    unsigned r = v.u + 0x7FFFu + ((v.u >> 16) & 1u);
    return (unsigned short)(r >> 16);
}

// tanh-form GELU approx: v * sigmoid(1.5957691*v*(1+0.044715*v^2)).
__device__ __forceinline__ float gelu_fast(float v) {
    const float z = 1.5957691216f * v * fmaf(0.044715f, v * v, 1.0f);
    return __fdividef(v, 1.0f + __expf(-z));
}

// ---------------------------------------------------------------------------
// A1 (wave-specialized, 9KB LDS, XCD-slab swizzled):
// block = (b, row h, chunk of 128 ch), 128 threads (2 waves), grid 3072.
// XCD-aware decomposition (T1): consecutive blockIdx round-robin across the
// 8 XCDs, so give XCD k the contiguous row slab r = k*64 .. k*64+63
// (r = b*HH + h, 512 rows total). The 3-row vertical halo (h-1,h,h+1) is
// then re-read from the SAME XCD's L2 instead of cross-XCD duplicate HBM
// misses (r10 measured FETCH = 146MB = 1.52x of x; this is the overfetch).
// chunk cycles fastest within the slab so row-neighbors are ~6 blocks apart.
// MFMA wave-specialization: wave0 = gelu x off_w (planes n<8),
// wave1 = center-x x wt_w (planes 8+n). 4 MFMA + 4 ds_read_b128 per quarter.
// Stores immediate per-quarter (r8: deferred accs spill to scratch).
// ---------------------------------------------------------------------------
__global__ __launch_bounds__(128, 4) void dq_conv_mfma(
    const float* __restrict__ x,      // (B, N, C)
    const float* __restrict__ dw_w,   // (C, 9)
    const float* __restrict__ dw_b,   // (C,)
    const float* __restrict__ off_w,  // (8, C)
    const float* __restrict__ wt_w,   // (8, C)
    float* __restrict__ offpart)      // (NCHUNK, 16, B*N)
{
    __shared__ unsigned short gl[16][144];   // gelu bf16: [col-in-quarter][ch]
    __shared__ unsigned short xh[16][144];   // center x bf16
    const int t = threadIdx.x;
    const int lane = t & 63, wv = t >> 6;
    // ---- XCD-slab swizzle (bijective on 3072 = 8 xcd x 64 rows x 6 chunks) ----
    const int xcd = blockIdx.x & 7;
    const int local = blockIdx.x >> 3;         // 0..383
    const int chunk = local % NCHUNK;
    const int r = xcd * (BB * HH / 8) + local / NCHUNK;   // global row 0..511
    const int h = r & (HH - 1);
    const int b = r >> 6;
    const int c = chunk * CHUNK + t;

    // ---- B fragments: wave0 = off_w, wave1 = wt_w (rows n<8 valid) ----
    const int n = lane & 15, kg = lane >> 4;
    const float* wsrc = (wv == 0) ? off_w : wt_w;
    short8 bfrag[4];
#pragma unroll
    for (int kt = 0; kt < 4; ++kt) {
        const bool valid = (n < 8);
        const float* src = wsrc + (valid ? n : 0) * CC + chunk * CHUNK + kt * 32 + kg * 8;
        short8 bf;
#pragma unroll
        for (int j = 0; j < 8; ++j) {
            const float v = valid ? src[j] : 0.f;
            bf[j] = (short)f2bf(v);
        }
        bfrag[kt] = bf;
    }

    float w9[9];
#pragma unroll
    for (int j = 0; j < 9; ++j) w9[j] = dw_w[c * 9 + j];
    const float bias = dw_b[c];
    const bool tv = (h > 0), bv = (h < HH - 1);
    // boundary rows: clamp pointer, zero the tap weights (no per-load selects)
    const float wt0 = tv ? w9[0] : 0.f, wt1 = tv ? w9[1] : 0.f, wt2 = tv ? w9[2] : 0.f;
    const float wb0 = bv ? w9[6] : 0.f, wb1 = bv ? w9[7] : 0.f, wb2 = bv ? w9[8] : 0.f;

    const float* base = x + (size_t)b * NN * CC + c;
    const float* rT = base + (size_t)((tv ? h - 1 : 0) * WW) * CC;   // h-1 (clamped)
    const float* rM = base + (size_t)(h * WW) * CC;                  // h
    const float* rB = base + (size_t)((bv ? h + 1 : h) * WW) * CC;   // h+1 (clamped)

    float cT[8], cM[8], cB[8], nT[8], nM[8], nB[8];
    float pT = 0.f, pM = 0.f, pB = 0.f;   // column w-1 carries

#pragma unroll
    for (int j = 0; j < 8; ++j) {
        const size_t o = (size_t)j * CC;
        cT[j] = rT[o]; cM[j] = rM[o]; cB[j] = rB[o];
    }

#pragma unroll
    for (int q = 0; q < 4; ++q) {
#pragma unroll
        for (int hb = 0; hb < 2; ++hb) {
            const int wb = q * 2 + hb;
            if (wb < 7) {
#pragma unroll
                for (int j = 0; j < 8; ++j) {
                    const size_t o = (size_t)(wb * 8 + 8 + j) * CC;
                    nT[j] = rT[o]; nM[j] = rM[o]; nB[j] = rB[o];
                }
            } else {
#pragma unroll
                for (int j = 0; j < 8; ++j) { nT[j] = 0.f; nM[j] = 0.f; nB[j] = 0.f; }
            }
#pragma unroll
            for (int j = 0; j < 8; ++j) {
                const float lT = j ? cT[j - 1] : pT;
                const float lM = j ? cM[j - 1] : pM;
                const float lB = j ? cB[j - 1] : pB;
                const float rTv = (j == 7) ? nT[0] : cT[j + 1];
                const float rMv = (j == 7) ? nM[0] : cM[j + 1];
                const float rBv = (j == 7) ? nB[0] : cB[j + 1];
                const float conv = lT * wt0 + cT[j] * wt1 + rTv * wt2
                                 + lM * w9[3] + cM[j] * w9[4] + rMv * w9[5]
                                 + lB * wb0 + cB[j] * wb1 + rBv * wb2;
                const int colq = hb * 8 + j;     // column within quarter
                gl[colq][t] = f2bf(gelu_fast(conv + bias));
                xh[colq][t] = f2bf(cM[j]);
            }
            pT = cT[7]; pM = cM[7]; pB = cB[7];
#pragma unroll
            for (int j = 0; j < 8; ++j) { cT[j] = nT[j]; cM[j] = nM[j]; cB[j] = nB[j]; }
        }

        __syncthreads();
        // wave 0: gelu x off_w; wave 1: center-x x wt_w. A-row = n (col in quarter).
        f32x4 acc = {0.f, 0.f, 0.f, 0.f};
        if (wv == 0) {
#pragma unroll
            for (int kt = 0; kt < 4; ++kt) {
                const short8 a = *(const short8*)&gl[n][kt * 32 + kg * 8];
                acc = __builtin_amdgcn_mfma_f32_16x16x32_bf16(a, bfrag[kt], acc, 0, 0, 0);
            }
        } else {
#pragma unroll
            for (int kt = 0; kt < 4; ++kt) {
                const short8 a = *(const short8*)&xh[n][kt * 32 + kg * 8];
                acc = __builtin_amdgcn_mfma_f32_16x16x32_bf16(a, bfrag[kt], acc, 0, 0, 0);
            }
        }
        // D: col n = plane (n<8 valid), rows kg*4..+3 = 4 consecutive positions
        if (n < 8) {
            const int plane = chunk * 16 + (wv ? 8 + n : n);
            const size_t gpos = (size_t)(b * NN) + h * WW + q * 16 + kg * 4;
            float4 st; st.x = acc[0]; st.y = acc[1]; st.z = acc[2]; st.w = acc[3];
            *(float4*)&offpart[(size_t)plane * (BB * NN) + gpos] = st;
        }
        if (q < 3) __syncthreads();
    }
}

// ---------------------------------------------------------------------------
// Combine (coalesced): sum 6 chunk partials, sigmoid gate, shift, clip.
// thread: o = t>>5 (0..7), pos = blk*32 + (t&31)  -> gpos-coalesced reads.
// ---------------------------------------------------------------------------
__global__ __launch_bounds__(256) void dq_combine(
    const float* __restrict__ offpart,  // (NCHUNK, 16, B*N)
    const float* __restrict__ off_b,
    const float* __restrict__ wt_b,
    float* __restrict__ ixiy)           // (2, B*G, N)
{
    const int t = threadIdx.x;
    const int o = t >> 5;
    const int gpos = blockIdx.x * 32 + (t & 31);
    const int b = gpos >> 12;
    const int hw = gpos & 4095;
    const int h = hw >> 6, w = hw & 63;

    float so = 0.f, sw = 0.f;
#pragma unroll
    for (int ch = 0; ch < NCHUNK; ++ch) {
        so += offpart[((size_t)(ch * 16 + o)) * (BB * NN) + gpos];
        sw += offpart[((size_t)(ch * 16 + 8 + o)) * (BB * NN) + gpos];
    }
    const float sig = 1.f / (1.f + __expf(-(sw + wt_b[o])));
    const float val = (so + off_b[o]) * sig;

    if (o < 4) {
        const float shx = (o == 2) ? -1.f : ((o == 3) ? 1.f : 0.f);
        const float ix = fminf(fmaxf((float)w + val + shx, 0.f), (float)(WW - 1));
        ixiy[(b * GG + o) * NN + hw] = ix;
    } else {
        const int g = o - 4;
        const float shy = (g == 0) ? -1.f : ((g == 1) ? 1.f : 0.f);
        const float iy = fminf(fmaxf((float)h + val + shy, 0.f), (float)(HH - 1));
        ixiy[BB * GG * NN + (b * GG + g) * NN + hw] = iy;
    }
}

// ---------------------------------------------------------------------------
// B: bilinear border sampling, float4-vectorized, XCD-swizzled (T1).
// 192 threads, 4 ch/thread; 8 coord loads per block broadcast via LDS.
// ---------------------------------------------------------------------------
__global__ __launch_bounds__(192) void dq_sample_vec(
    const float* __restrict__ x,        // (B, N, C)
    const float* __restrict__ ixiy,     // (2, B*G, N)
    float* __restrict__ out)            // (B, N, C)
{
    __shared__ float ixy[8];            // ix[4], iy[4]
    const int t = threadIdx.x;
    // XCD-aware bijective swizzle: 32768 blocks % 8 XCDs == 0; each XCD walks
    // a contiguous chunk of positions -> bilinear rows stay L2-resident.
    const int p = (blockIdx.x & 7) * (BB * NN / 8) + (blockIdx.x >> 3);
    const int b = p >> 12;
    const int hw = p & 4095;

    if (t < 8) {
        const int g = t & 3;
        const int plane = (t >> 2) * (BB * GG * NN);
        ixy[t] = ixiy[plane + (b * GG + g) * NN + hw];
    }
    __syncthreads();

    const int g = t / 48;               // 48 threads x 4ch = 192 ch per group
    const float ix = ixy[g], iy = ixy[4 + g];
    const float x0f = floorf(ix), y0f = floorf(iy);
    const float wx = ix - x0f, wy = iy - y0f;
    const int x0 = (int)x0f, y0 = (int)y0f;
    const int x1 = min(x0 + 1, WW - 1), y1 = min(y0 + 1, HH - 1);
    const int c4 = t * 4;
    const float* xb = x + (size_t)b * NN * CC;
    const float4 v00 = *(const float4*)(xb + (size_t)(y0 * WW + x0) * CC + c4);
    const float4 v01 = *(const float4*)(xb + (size_t)(y0 * WW + x1) * CC + c4);
    const float4 v10 = *(const float4*)(xb + (size_t)(y1 * WW + x0) * CC + c4);
    const float4 v11 = *(const float4*)(xb + (size_t)(y1 * WW + x1) * CC + c4);
    const float w00 = (1.f - wx) * (1.f - wy), w01 = wx * (1.f - wy);
    const float w10 = (1.f - wx) * wy,         w11 = wx * wy;
    float4 r;
    r.x = v00.x * w00 + v01.x * w01 + v10.x * w10 + v11.x * w11;
    r.y = v00.y * w00 + v01.y * w01 + v10.y * w10 + v11.y * w11;
    r.z = v00.z * w00 + v01.z * w01 + v10.z * w10 + v11.z * w11;
    r.w = v00.w * w00 + v01.w * w01 + v10.w * w10 + v11.w * w11;
    *(float4*)(out + (size_t)p * CC + c4) = r;
}

// ---------------------------------------------------------------------------
// Fallback (small ws): round-1 fused offsets kernel + scalar sampler.
// ---------------------------------------------------------------------------
__global__ __launch_bounds__(256) void dqshift_offsets_kernel(
    const float* __restrict__ x, const float* __restrict__ dw_w,
    const float* __restrict__ dw_b, const float* __restrict__ off_w,
    const float* __restrict__ off_b, const float* __restrict__ wt_w,
    const float* __restrict__ wt_b, float* __restrict__ ixiy)
{
    const int wave = threadIdx.x >> 6;
    const int lane = threadIdx.x & 63;
    const int p = blockIdx.x * 4 + wave;
    const int b = p >> 12;
    const int hw = p & 4095;
    const int h = hw >> 6;
    const int w = hw & 63;
    const float* xb = x + (size_t)b * NN * CC;
    float accO[8], accW[8];
#pragma unroll
    for (int o = 0; o < 8; ++o) { accO[o] = 0.f; accW[o] = 0.f; }
    for (int k = 0; k < CC / 64; ++k) {
        const int c = lane + (k << 6);
        float conv = 0.f, xc = 0.f;
#pragma unroll
        for (int dy = -1; dy <= 1; ++dy) {
            const int hh = h + dy;
            const bool vy = (hh >= 0) && (hh < HH);
#pragma unroll
            for (int dx = -1; dx <= 1; ++dx) {
                const int ww = w + dx;
                const bool vv = vy && (ww >= 0) && (ww < WW);
                const float tt = vv ? xb[(size_t)(hh * WW + ww) * CC + c] : 0.f;
                if (dy == 0 && dx == 0) xc = tt;
                conv = fmaf(tt, dw_w[c * 9 + (dy + 1) * 3 + (dx + 1)], conv);
            }
        }
        const float gv = conv + dw_b[c];
        const float gle = 0.5f * gv * (1.0f + erff(gv * 0.70710678118654752f));
#pragma unroll
        for (int o = 0; o < 8; ++o) {
            accO[o] = fmaf(gle, off_w[o * CC + c], accO[o]);
            accW[o] = fmaf(xc, wt_w[o * CC + c], accW[o]);
        }
    }
#pragma unroll
    for (int o = 0; o < 8; ++o) {
#pragma unroll
        for (int s = 32; s > 0; s >>= 1) {
            accO[o] += __shfl_xor(accO[o], s, 64);
            accW[o] += __shfl_xor(accW[o], s, 64);
        }
    }
    if (lane == 0) {
        const float shx[4] = {0.f, 0.f, -1.f, 1.f};
        const float shy[4] = {-1.f, 1.f, 0.f, 0.f};
#pragma unroll
        for (int g = 0; g < 4; ++g) {
            const float sx = 1.f / (1.f + expf(-(accW[g] + wt_b[g])));
            const float sy = 1.f / (1.f + expf(-(accW[4 + g] + wt_b[4 + g])));
            const float ox = (accO[g] + off_b[g]) * sx + shx[g];
            const float oy = (accO[4 + g] + off_b[4 + g]) * sy + shy[g];
            const float ix = fminf(fmaxf((float)w + ox, 0.f), (float)(WW - 1));
            const float iy = fminf(fmaxf((float)h + oy, 0.f), (float)(HH - 1));
            const int idx = (b * GG + g) * NN + hw;
            ixiy[idx] = ix;
            ixiy[BB * GG * NN + idx] = iy;
        }
    }
}

__global__ __launch_bounds__(256) void dqshift_sample_kernel(
    const float* __restrict__ x,
    const float* __restrict__ ixiy,
    float* __restrict__ out)
{
    const int p = blockIdx.x;
    const int b = p >> 12;
    const int hw = p & 4095;
    const float* xb = x + (size_t)b * NN * CC;
    float* ob = out + (size_t)p * CC;

#pragma unroll
    for (int k = 0; k < 3; ++k) {
        const int c = threadIdx.x + (k << 8);
        const int g = c / (CC / GG);
        const int idx = (b * GG + g) * NN + hw;
        const float ix = ixiy[idx];
        const float iy = ixiy[BB * GG * NN + idx];
        const float x0f = floorf(ix);
        const float y0f = floorf(iy);
        const float wx = ix - x0f;
        const float wy = iy - y0f;
        const int x0 = (int)x0f;
        const int y0 = (int)y0f;
        const int x1 = min(x0 + 1, WW - 1);
        const int y1 = min(y0 + 1, HH - 1);
        const float* r0 = xb + (size_t)(y0 * WW) * CC + c;
        const float* r1 = xb + (size_t)(y1 * WW) * CC + c;
        const float v00 = r0[(size_t)x0 * CC];
        const float v01 = r0[(size_t)x1 * CC];
        const float v10 = r1[(size_t)x0 * CC];
        const float v11 = r1[(size_t)x1 * CC];
        ob[c] = v00 * (1.f - wx) * (1.f - wy) + v01 * wx * (1.f - wy)
              + v10 * (1.f - wx) * wy + v11 * wx * wy;
    }
}

extern "C" void kernel_launch(void* const* d_in, const int* in_sizes, int n_in,
                              void* d_out, int out_size, void* d_ws, size_t ws_size,
                              hipStream_t stream) {
    const float* x     = (const float*)d_in[0];
    const float* dw_w  = (const float*)d_in[1];
    const float* dw_b  = (const float*)d_in[2];
    const float* off_w = (const float*)d_in[3];
    const float* off_b = (const float*)d_in[4];
    const float* wt_w  = (const float*)d_in[5];
    const float* wt_b  = (const float*)d_in[6];

    float* ixiy = (float*)d_ws;                              // 1 MiB
    float* offpart = (float*)d_ws + 2 * BB * GG * NN;        // 12.58 MiB
    const size_t need = (size_t)(2 * BB * GG * NN + NCHUNK * 16 * BB * NN) * 4;

    if (ws_size >= need) {
        dq_conv_mfma<<<BB * HH * NCHUNK, 128, 0, stream>>>(
            x, dw_w, dw_b, off_w, wt_w, offpart);
        dq_combine<<<BB * NN / 32, 256, 0, stream>>>(
            offpart, off_b, wt_b, ixiy);
        dq_sample_vec<<<BB * NN, 192, 0, stream>>>(
            x, ixiy, (float*)d_out);
    } else {
        dqshift_offsets_kernel<<<BB * NN / 4, 256, 0, stream>>>(
            x, dw_w, dw_b, off_w, off_b, wt_w, wt_b, ixiy);
        dqshift_sample_kernel<<<BB * NN, 256, 0, stream>>>(x, ixiy, (float*)d_out);
    }
}